// Round 1
// baseline (6762.833 us; speedup 1.0000x reference)
//
#include <hip/hip_runtime.h>
#include <hip/hip_bf16.h>

#define B_    8
#define S_    2048
#define HID_  512
#define H_    8
#define D_    64
#define FF_   2048
#define QKVB_ 1544   // H*(3*D+1) = 8*193

// ---------------------------------------------------------------------------
// Generic tiled GEMM:  C[m,n] = epilogue( sum_k A[m,k] * W[n,k] )
// BM=BN=64, BK=16, 256 threads, 4x4 accumulators per thread.
// ASWAP: A row m (= s*B+b) is read from row b*S+s (input-proj transpose fusion)
// ---------------------------------------------------------------------------
template<bool BIAS, bool RELU, bool RES, bool ASWAP>
__global__ __launch_bounds__(256) void gemm_bt(
    const float* __restrict__ A, const float* __restrict__ Wt,
    const float* __restrict__ bias, const float* __restrict__ res,
    float* __restrict__ C, int M, int N, int K)
{
  __shared__ __align__(16) float As[16][68];
  __shared__ __align__(16) float Ws[16][68];
  const int bm = blockIdx.y * 64, bn = blockIdx.x * 64;
  const int tid = threadIdx.x;
  const int tx = tid & 15, ty = tid >> 4;
  const int lk = tid & 15, lr = tid >> 4;
  float acc[4][4] = {};

  for (int k0 = 0; k0 < K; k0 += 16) {
    #pragma unroll
    for (int rr = 0; rr < 4; ++rr) {
      int i = lr + rr * 16;
      int m = bm + i;
      int arow = ASWAP ? ((m & (B_ - 1)) * S_ + (m >> 3)) : m;
      As[lk][i] = A[(size_t)arow * K + k0 + lk];
    }
    #pragma unroll
    for (int rr = 0; rr < 4; ++rr) {
      int j = lr + rr * 16;
      int n = bn + j;
      Ws[lk][j] = (n < N) ? Wt[(size_t)n * K + k0 + lk] : 0.f;
    }
    __syncthreads();
    #pragma unroll
    for (int kk = 0; kk < 16; ++kk) {
      float4 av = *(const float4*)&As[kk][ty * 4];
      float4 wv = *(const float4*)&Ws[kk][tx * 4];
      float a4[4] = {av.x, av.y, av.z, av.w};
      float w4[4] = {wv.x, wv.y, wv.z, wv.w};
      #pragma unroll
      for (int a = 0; a < 4; ++a)
        #pragma unroll
        for (int b = 0; b < 4; ++b)
          acc[a][b] = fmaf(a4[a], w4[b], acc[a][b]);
    }
    __syncthreads();
  }

  #pragma unroll
  for (int a = 0; a < 4; ++a) {
    int m = bm + ty * 4 + a;
    #pragma unroll
    for (int b = 0; b < 4; ++b) {
      int n = bn + tx * 4 + b;
      if (n < N) {
        float v = acc[a][b];
        if (BIAS) v += bias[n];
        if (RES)  v += res[(size_t)m * N + n];
        if (RELU) v = fmaxf(v, 0.f);
        C[(size_t)m * N + n] = v;
      }
    }
  }
}

// ---------------------------------------------------------------------------
// LayerNorm over HID=512 per row; one wave per row, 8 floats/lane.
// ---------------------------------------------------------------------------
__global__ __launch_bounds__(64) void ln_k(const float* __restrict__ x,
    const float* __restrict__ g, const float* __restrict__ bt,
    float* __restrict__ o)
{
  size_t row = blockIdx.x;
  int lane = threadIdx.x;
  const float4* xr = (const float4*)(x + row * HID_);
  float4 v0 = xr[lane];
  float4 v1 = xr[64 + lane];
  float s  = v0.x + v0.y + v0.z + v0.w + v1.x + v1.y + v1.z + v1.w;
  float ss = v0.x*v0.x + v0.y*v0.y + v0.z*v0.z + v0.w*v0.w
           + v1.x*v1.x + v1.y*v1.y + v1.z*v1.z + v1.w*v1.w;
  #pragma unroll
  for (int off = 32; off; off >>= 1) {
    s  += __shfl_xor(s, off);
    ss += __shfl_xor(ss, off);
  }
  float mean = s * (1.f / HID_);
  float inv  = rsqrtf(ss * (1.f / HID_) - mean * mean + 1e-5f);
  const float4* gv = (const float4*)g;
  const float4* bv = (const float4*)bt;
  float4 g0 = gv[lane], g1 = gv[64 + lane];
  float4 b0 = bv[lane], b1 = bv[64 + lane];
  float4 r0, r1;
  r0.x = (v0.x - mean) * inv * g0.x + b0.x;
  r0.y = (v0.y - mean) * inv * g0.y + b0.y;
  r0.z = (v0.z - mean) * inv * g0.z + b0.z;
  r0.w = (v0.w - mean) * inv * g0.w + b0.w;
  r1.x = (v1.x - mean) * inv * g1.x + b1.x;
  r1.y = (v1.y - mean) * inv * g1.y + b1.y;
  r1.z = (v1.z - mean) * inv * g1.z + b1.z;
  r1.w = (v1.w - mean) * inv * g1.w + b1.w;
  float4* ov = (float4*)(o + row * HID_);
  ov[lane] = r0;
  ov[64 + lane] = r1;
}

// ---------------------------------------------------------------------------
// In-place softmax(q), softmax(k), sigmoid(beta) per (s,b,h) row of qkvb.
// One wave per row; row index r = m*H + h where m = s*B+b.
// ---------------------------------------------------------------------------
__global__ __launch_bounds__(64) void qkvb_transform(float* __restrict__ qkvb)
{
  size_t r = blockIdx.x;
  float* base = qkvb + (r >> 3) * (size_t)QKVB_ + (r & 7) * 193;
  int lane = threadIdx.x;
  float q = base[lane], k = base[64 + lane];
  float mq = q, mk = k;
  #pragma unroll
  for (int off = 32; off; off >>= 1) {
    mq = fmaxf(mq, __shfl_xor(mq, off));
    mk = fmaxf(mk, __shfl_xor(mk, off));
  }
  float eq = __expf(q - mq), ek = __expf(k - mk);
  float sq = eq, sk = ek;
  #pragma unroll
  for (int off = 32; off; off >>= 1) { sq += __shfl_xor(sq, off); sk += __shfl_xor(sk, off); }
  base[lane]      = eq / sq;
  base[64 + lane] = ek / sk;
  if (lane == 0) { float bb = base[192]; base[192] = 1.f / (1.f + __expf(-bb)); }
}

// ---------------------------------------------------------------------------
// Delta-rule scan. One wave per (b,h); lane d owns row d of W (64 VGPRs).
// W_t = W_{t-1} + beta_t (v_t - W_{t-1} k_t) k_t^T ; out_t = W_t q_t
// ---------------------------------------------------------------------------
#define CH_ 16
__global__ __launch_bounds__(64, 1) void delta_scan(const float* __restrict__ qkvb,
                                                    float* __restrict__ attn)
{
  const int p = blockIdx.x;     // 0..63
  const int b = p & 7, h = p >> 3;
  const int lane = threadIdx.x; // row d of W
  float Wr[64];
  #pragma unroll
  for (int e = 0; e < 64; ++e) Wr[e] = 0.f;
  __shared__ __align__(16) float ks[CH_][64], qs[CH_][64], vs[CH_][64];
  __shared__ float bs[CH_];

  for (int t0 = 0; t0 < S_; t0 += CH_) {
    for (int c = 0; c < CH_; ++c) {
      const float* base = qkvb + ((size_t)(t0 + c) * B_ + b) * QKVB_ + h * 193;
      qs[c][lane] = base[lane];
      ks[c][lane] = base[64 + lane];
      vs[c][lane] = base[128 + lane];
    }
    if (lane < CH_)
      bs[lane] = qkvb[((size_t)(t0 + lane) * B_ + b) * QKVB_ + h * 193 + 192];
    __syncthreads();

    for (int c = 0; c < CH_; ++c) {
      float kreg[64], qreg[64];
      #pragma unroll
      for (int e = 0; e < 64; e += 4) {
        *(float4*)&kreg[e] = *(const float4*)&ks[c][e];
        *(float4*)&qreg[e] = *(const float4*)&qs[c][e];
      }
      float wk0 = 0.f, wk1 = 0.f, wk2 = 0.f, wk3 = 0.f;
      #pragma unroll
      for (int e = 0; e < 64; e += 4) {
        wk0 = fmaf(Wr[e + 0], kreg[e + 0], wk0);
        wk1 = fmaf(Wr[e + 1], kreg[e + 1], wk1);
        wk2 = fmaf(Wr[e + 2], kreg[e + 2], wk2);
        wk3 = fmaf(Wr[e + 3], kreg[e + 3], wk3);
      }
      float wk = (wk0 + wk1) + (wk2 + wk3);
      float vn = bs[c] * (vs[c][lane] - wk);
      float o0 = 0.f, o1 = 0.f, o2 = 0.f, o3 = 0.f;
      #pragma unroll
      for (int e = 0; e < 64; e += 4) {
        Wr[e + 0] = fmaf(vn, kreg[e + 0], Wr[e + 0]);
        Wr[e + 1] = fmaf(vn, kreg[e + 1], Wr[e + 1]);
        Wr[e + 2] = fmaf(vn, kreg[e + 2], Wr[e + 2]);
        Wr[e + 3] = fmaf(vn, kreg[e + 3], Wr[e + 3]);
        o0 = fmaf(Wr[e + 0], qreg[e + 0], o0);
        o1 = fmaf(Wr[e + 1], qreg[e + 1], o1);
        o2 = fmaf(Wr[e + 2], qreg[e + 2], o2);
        o3 = fmaf(Wr[e + 3], qreg[e + 3], o3);
      }
      attn[((size_t)(t0 + c) * B_ + b) * HID_ + h * 64 + lane] = (o0 + o1) + (o2 + o3);
    }
    __syncthreads();
  }
}

// ---------------------------------------------------------------------------
// [S,B,512] -> [B,S,512]
// ---------------------------------------------------------------------------
__global__ __launch_bounds__(128) void transpose_sb_to_bs(const float* __restrict__ in,
                                                          float* __restrict__ out)
{
  size_t m = blockIdx.x;            // s*B + b
  size_t s = m >> 3, b = m & 7;
  const float4* src = (const float4*)(in + m * HID_);
  float4* dst = (float4*)(out + (b * (size_t)S_ + s) * HID_);
  dst[threadIdx.x] = src[threadIdx.x];
}

// ---------------------------------------------------------------------------
extern "C" void kernel_launch(void* const* d_in, const int* in_sizes, int n_in,
                              void* d_out, int out_size, void* d_ws, size_t ws_size,
                              hipStream_t stream)
{
  const float* x        = (const float*)d_in[0];
  const float* ip_w     = (const float*)d_in[1];
  const float* ip_b     = (const float*)d_in[2];
  const float* fw_ln_g  = (const float*)d_in[3];
  const float* fw_ln_b  = (const float*)d_in[4];
  const float* fw_slow_w = (const float*)d_in[5];
  const float* fw_out_w  = (const float*)d_in[6];
  const float* ff_ln_g  = (const float*)d_in[7];
  const float* ff_ln_b  = (const float*)d_in[8];
  const float* ff_w1    = (const float*)d_in[9];
  const float* ff_b1    = (const float*)d_in[10];
  const float* ff_w2    = (const float*)d_in[11];
  const float* ff_b2    = (const float*)d_in[12];
  float* out = (float*)d_out;

  const int M = B_ * S_;  // 16384

  // workspace layout: cur [M*512] | big [M*2056]  (qkvb M*1544 ++ attn M*512 ; aliased with ffn-hidden M*2048)
  size_t need = ((size_t)M * HID_ + (size_t)M * (QKVB_ + HID_)) * sizeof(float);
  if (ws_size < need) return;  // insufficient scratch -> fail validation loudly

  float* cur  = (float*)d_ws;
  float* big  = cur + (size_t)M * HID_;
  float* qkvb = big;
  float* attn = big + (size_t)M * QKVB_;
  float* tmp  = out;  // LN output scratch; fully overwritten by final transpose

  dim3 blk(256);

  // 1. input projection (fused [B,S]->[S,B] transpose): cur = x @ ip_w^T + ip_b
  gemm_bt<true, false, false, true><<<dim3(HID_ / 64, M / 64), blk, 0, stream>>>(
      x, ip_w, ip_b, nullptr, cur, M, HID_, HID_);

  for (int layer = 0; layer < 2; ++layer) {
    const float* sw = fw_slow_w + (size_t)layer * QKVB_ * HID_;
    const float* ow = fw_out_w  + (size_t)layer * HID_ * HID_;

    // fast_ff
    ln_k<<<M, 64, 0, stream>>>(cur, fw_ln_g + layer * HID_, fw_ln_b + layer * HID_, tmp);
    gemm_bt<false, false, false, false><<<dim3((QKVB_ + 63) / 64, M / 64), blk, 0, stream>>>(
        tmp, sw, nullptr, nullptr, qkvb, M, QKVB_, HID_);
    qkvb_transform<<<(size_t)M * H_, 64, 0, stream>>>(qkvb);
    delta_scan<<<64, 64, 0, stream>>>(qkvb, attn);
    gemm_bt<false, false, true, false><<<dim3(HID_ / 64, M / 64), blk, 0, stream>>>(
        attn, ow, nullptr, cur, cur, M, HID_, HID_);

    if (layer == 0) {
      // FFN
      ln_k<<<M, 64, 0, stream>>>(cur, ff_ln_g, ff_ln_b, tmp);
      gemm_bt<true, true, false, false><<<dim3(FF_ / 64, M / 64), blk, 0, stream>>>(
          tmp, ff_w1, ff_b1, nullptr, big, M, FF_, HID_);
      gemm_bt<true, false, true, false><<<dim3(HID_ / 64, M / 64), blk, 0, stream>>>(
          big, ff_w2, ff_b2, cur, cur, M, HID_, FF_);
    }
  }

  // final [S,B,512] -> [B,S,512]
  transpose_sb_to_bs<<<M, 128, 0, stream>>>(cur, out);
}

// Round 2
// 3985.815 us; speedup vs baseline: 1.6967x; 1.6967x over previous
//
#include <hip/hip_runtime.h>
#include <hip/hip_bf16.h>

#define B_    8
#define S_    2048
#define HID_  512
#define H_    8
#define D_    64
#define FF_   2048
#define QKVB_ 1544   // H*(3*D+1) = 8*193
#define CPAD  65

// ---------------------------------------------------------------------------
// Generic tiled GEMM:  C[m,n] = epilogue( sum_k A[m,k] * W[n,k] )
// ---------------------------------------------------------------------------
template<bool BIAS, bool RELU, bool RES, bool ASWAP>
__global__ __launch_bounds__(256) void gemm_bt(
    const float* __restrict__ A, const float* __restrict__ Wt,
    const float* __restrict__ bias, const float* __restrict__ res,
    float* __restrict__ C, int M, int N, int K)
{
  __shared__ __align__(16) float As[16][68];
  __shared__ __align__(16) float Ws[16][68];
  const int bm = blockIdx.y * 64, bn = blockIdx.x * 64;
  const int tid = threadIdx.x;
  const int tx = tid & 15, ty = tid >> 4;
  const int lk = tid & 15, lr = tid >> 4;
  float acc[4][4] = {};

  for (int k0 = 0; k0 < K; k0 += 16) {
    #pragma unroll
    for (int rr = 0; rr < 4; ++rr) {
      int i = lr + rr * 16;
      int m = bm + i;
      int arow = ASWAP ? ((m & (B_ - 1)) * S_ + (m >> 3)) : m;
      As[lk][i] = A[(size_t)arow * K + k0 + lk];
    }
    #pragma unroll
    for (int rr = 0; rr < 4; ++rr) {
      int j = lr + rr * 16;
      int n = bn + j;
      Ws[lk][j] = (n < N) ? Wt[(size_t)n * K + k0 + lk] : 0.f;
    }
    __syncthreads();
    #pragma unroll
    for (int kk = 0; kk < 16; ++kk) {
      float4 av = *(const float4*)&As[kk][ty * 4];
      float4 wv = *(const float4*)&Ws[kk][tx * 4];
      float a4[4] = {av.x, av.y, av.z, av.w};
      float w4[4] = {wv.x, wv.y, wv.z, wv.w};
      #pragma unroll
      for (int a = 0; a < 4; ++a)
        #pragma unroll
        for (int b = 0; b < 4; ++b)
          acc[a][b] = fmaf(a4[a], w4[b], acc[a][b]);
    }
    __syncthreads();
  }

  #pragma unroll
  for (int a = 0; a < 4; ++a) {
    int m = bm + ty * 4 + a;
    #pragma unroll
    for (int b = 0; b < 4; ++b) {
      int n = bn + tx * 4 + b;
      if (n < N) {
        float v = acc[a][b];
        if (BIAS) v += bias[n];
        if (RES)  v += res[(size_t)m * N + n];
        if (RELU) v = fmaxf(v, 0.f);
        C[(size_t)m * N + n] = v;
      }
    }
  }
}

// ---------------------------------------------------------------------------
// LayerNorm over HID=512 per row; one wave per row.
// ---------------------------------------------------------------------------
__global__ __launch_bounds__(64) void ln_k(const float* __restrict__ x,
    const float* __restrict__ g, const float* __restrict__ bt,
    float* __restrict__ o)
{
  size_t row = blockIdx.x;
  int lane = threadIdx.x;
  const float4* xr = (const float4*)(x + row * HID_);
  float4 v0 = xr[lane];
  float4 v1 = xr[64 + lane];
  float s  = v0.x + v0.y + v0.z + v0.w + v1.x + v1.y + v1.z + v1.w;
  float ss = v0.x*v0.x + v0.y*v0.y + v0.z*v0.z + v0.w*v0.w
           + v1.x*v1.x + v1.y*v1.y + v1.z*v1.z + v1.w*v1.w;
  #pragma unroll
  for (int off = 32; off; off >>= 1) {
    s  += __shfl_xor(s, off);
    ss += __shfl_xor(ss, off);
  }
  float mean = s * (1.f / HID_);
  float inv  = rsqrtf(ss * (1.f / HID_) - mean * mean + 1e-5f);
  const float4* gv = (const float4*)g;
  const float4* bv = (const float4*)bt;
  float4 g0 = gv[lane], g1 = gv[64 + lane];
  float4 b0 = bv[lane], b1 = bv[64 + lane];
  float4 r0, r1;
  r0.x = (v0.x - mean) * inv * g0.x + b0.x;
  r0.y = (v0.y - mean) * inv * g0.y + b0.y;
  r0.z = (v0.z - mean) * inv * g0.z + b0.z;
  r0.w = (v0.w - mean) * inv * g0.w + b0.w;
  r1.x = (v1.x - mean) * inv * g1.x + b1.x;
  r1.y = (v1.y - mean) * inv * g1.y + b1.y;
  r1.z = (v1.z - mean) * inv * g1.z + b1.z;
  r1.w = (v1.w - mean) * inv * g1.w + b1.w;
  float4* ov = (float4*)(o + row * HID_);
  ov[lane] = r0;
  ov[64 + lane] = r1;
}

// ---------------------------------------------------------------------------
// In-place softmax(q), softmax(k), sigmoid(beta) per (s,b,h) row of qkvb.
// ---------------------------------------------------------------------------
__global__ __launch_bounds__(64) void qkvb_transform(float* __restrict__ qkvb)
{
  size_t r = blockIdx.x;
  float* base = qkvb + (r >> 3) * (size_t)QKVB_ + (r & 7) * 193;
  int lane = threadIdx.x;
  float q = base[lane], k = base[64 + lane];
  float mq = q, mk = k;
  #pragma unroll
  for (int off = 32; off; off >>= 1) {
    mq = fmaxf(mq, __shfl_xor(mq, off));
    mk = fmaxf(mk, __shfl_xor(mk, off));
  }
  float eq = __expf(q - mq), ek = __expf(k - mk);
  float sq = eq, sk = ek;
  #pragma unroll
  for (int off = 32; off; off >>= 1) { sq += __shfl_xor(sq, off); sk += __shfl_xor(sk, off); }
  base[lane]      = eq / sq;
  base[64 + lane] = ek / sk;
  if (lane == 0) { float bb = base[192]; base[192] = 1.f / (1.f + __expf(-bb)); }
}

// ---------------------------------------------------------------------------
// Chunked delta-rule scan (WY form). One 256-thread block per (b,h).
// Per chunk of C=64 steps, with W0 = state at chunk entry:
//   A  = strict_tril(diag(beta) K K^T)           (64x64)
//   (I+A) U = diag(beta) (V - K W0^T)            (blocked forward subst.)
//   Out = Q W0^T + tril(Q K^T, incl diag) U
//   W1  = W0 + U^T K
// ---------------------------------------------------------------------------
__global__ __launch_bounds__(256, 1) void delta_chunk(const float* __restrict__ qkvb,
                                                      float* __restrict__ attn)
{
  __shared__ float Wst[64][CPAD];  // state W[d][e]
  __shared__ float Kc [64][CPAD];
  __shared__ float Qc [64][CPAD];
  __shared__ float Am [64][CPAD];  // A, then reused for G
  __shared__ float Um [64][CPAD];  // rhs -> U
  __shared__ float bet[64];

  const int p = blockIdx.x;          // 0..63
  const int b = p & 7, h = p >> 3;
  const int tid = threadIdx.x;
  const int tx = tid & 15, ty = tid >> 4;  // 4x4 tile: rows 4ty.., cols 4tx..
  const int wid = tid >> 6, lane = tid & 63;
  const size_t hoff = (size_t)h * 193;

  for (int i = tid; i < 64 * CPAD; i += 256) (&Wst[0][0])[i] = 0.f;
  __syncthreads();

  for (int t0 = 0; t0 < S_; t0 += 64) {
    // ---- stage K, Q, beta into LDS (coalesced rows of 64 floats) ----
    #pragma unroll
    for (int i = 0; i < 16; ++i) {
      int id = i * 256 + tid, row = id >> 6, col = id & 63;
      size_t gb = ((size_t)(t0 + row) * B_ + b) * QKVB_ + hoff;
      Qc[row][col] = qkvb[gb + col];
      Kc[row][col] = qkvb[gb + 64 + col];
    }
    if (tid < 64) bet[tid] = qkvb[((size_t)(t0 + tid) * B_ + b) * QKVB_ + hoff + 192];
    __syncthreads();

    // ---- A = beta_t * (K K^T)  (full 64x64, only lower-strict consumed) ----
    {
      float acc[4][4] = {};
      #pragma unroll 8
      for (int e = 0; e < 64; ++e) {
        float xr[4], yc[4];
        #pragma unroll
        for (int r = 0; r < 4; ++r) xr[r] = Kc[4 * ty + r][e];
        #pragma unroll
        for (int c = 0; c < 4; ++c) yc[c] = Kc[4 * tx + c][e];
        #pragma unroll
        for (int r = 0; r < 4; ++r)
          #pragma unroll
          for (int c = 0; c < 4; ++c) acc[r][c] = fmaf(xr[r], yc[c], acc[r][c]);
      }
      #pragma unroll
      for (int r = 0; r < 4; ++r) {
        float bt_ = bet[4 * ty + r];
        #pragma unroll
        for (int c = 0; c < 4; ++c) Am[4 * ty + r][4 * tx + c] = bt_ * acc[r][c];
      }
    }
    // ---- U(rhs) = beta_t * (V - K W0^T) ----
    {
      float acc[4][4] = {};
      #pragma unroll 8
      for (int e = 0; e < 64; ++e) {
        float xr[4], yc[4];
        #pragma unroll
        for (int r = 0; r < 4; ++r) xr[r] = Kc[4 * ty + r][e];
        #pragma unroll
        for (int c = 0; c < 4; ++c) yc[c] = Wst[4 * tx + c][e];
        #pragma unroll
        for (int r = 0; r < 4; ++r)
          #pragma unroll
          for (int c = 0; c < 4; ++c) acc[r][c] = fmaf(xr[r], yc[c], acc[r][c]);
      }
      #pragma unroll
      for (int r = 0; r < 4; ++r) {
        float bt_ = bet[4 * ty + r];
        size_t gb = ((size_t)(t0 + 4 * ty + r) * B_ + b) * QKVB_ + hoff + 128;
        #pragma unroll
        for (int c = 0; c < 4; ++c) {
          float v = qkvb[gb + 4 * tx + c];
          Um[4 * ty + r][4 * tx + c] = bt_ * (v - acc[r][c]);
        }
      }
    }
    __syncthreads();

    // ---- blocked forward substitution: (I+A) U = rhs ----
    #pragma unroll 1
    for (int blk = 0; blk < 4; ++blk) {
      if (wid == blk) {
        const int r0 = blk * 16;
        float u[16];
        #pragma unroll
        for (int i = 0; i < 16; ++i) u[i] = Um[r0 + i][lane];
        #pragma unroll
        for (int j = 0; j < 15; ++j) {
          float uj = u[j];
          #pragma unroll
          for (int t = j + 1; t < 16; ++t)
            u[t] = fmaf(-Am[r0 + t][r0 + j], uj, u[t]);
        }
        #pragma unroll
        for (int i = 0; i < 16; ++i) Um[r0 + i][lane] = u[i];
      }
      __syncthreads();
      if (wid > blk) {
        const int r0 = blk * 16, rw = wid * 16;
        float u[16];
        #pragma unroll
        for (int i = 0; i < 16; ++i) u[i] = Um[rw + i][lane];
        #pragma unroll
        for (int j = 0; j < 16; ++j) {
          float uj = Um[r0 + j][lane];
          #pragma unroll
          for (int i = 0; i < 16; ++i)
            u[i] = fmaf(-Am[rw + i][r0 + j], uj, u[i]);
        }
        #pragma unroll
        for (int i = 0; i < 16; ++i) Um[rw + i][lane] = u[i];
      }
      __syncthreads();
    }

    // ---- G = tril(Q K^T, incl diag) into Am ----
    {
      float acc[4][4] = {};
      #pragma unroll 8
      for (int e = 0; e < 64; ++e) {
        float xr[4], yc[4];
        #pragma unroll
        for (int r = 0; r < 4; ++r) xr[r] = Qc[4 * ty + r][e];
        #pragma unroll
        for (int c = 0; c < 4; ++c) yc[c] = Kc[4 * tx + c][e];
        #pragma unroll
        for (int r = 0; r < 4; ++r)
          #pragma unroll
          for (int c = 0; c < 4; ++c) acc[r][c] = fmaf(xr[r], yc[c], acc[r][c]);
      }
      #pragma unroll
      for (int r = 0; r < 4; ++r)
        #pragma unroll
        for (int c = 0; c < 4; ++c)
          Am[4 * ty + r][4 * tx + c] = (4 * tx + c <= 4 * ty + r) ? acc[r][c] : 0.f;
    }
    __syncthreads();

    // ---- Out = Q W0^T + G U ; store to attn ----
    {
      float acc[4][4] = {};
      #pragma unroll 8
      for (int e = 0; e < 64; ++e) {
        float xr[4], yc[4];
        #pragma unroll
        for (int r = 0; r < 4; ++r) xr[r] = Qc[4 * ty + r][e];
        #pragma unroll
        for (int c = 0; c < 4; ++c) yc[c] = Wst[4 * tx + c][e];
        #pragma unroll
        for (int r = 0; r < 4; ++r)
          #pragma unroll
          for (int c = 0; c < 4; ++c) acc[r][c] = fmaf(xr[r], yc[c], acc[r][c]);
      }
      #pragma unroll 8
      for (int j = 0; j < 64; ++j) {
        float xr[4], yc[4];
        #pragma unroll
        for (int r = 0; r < 4; ++r) xr[r] = Am[4 * ty + r][j];
        #pragma unroll
        for (int c = 0; c < 4; ++c) yc[c] = Um[j][4 * tx + c];
        #pragma unroll
        for (int r = 0; r < 4; ++r)
          #pragma unroll
          for (int c = 0; c < 4; ++c) acc[r][c] = fmaf(xr[r], yc[c], acc[r][c]);
      }
      #pragma unroll
      for (int r = 0; r < 4; ++r) {
        float4 o4 = make_float4(acc[r][0], acc[r][1], acc[r][2], acc[r][3]);
        *(float4*)&attn[((size_t)(t0 + 4 * ty + r) * B_ + b) * HID_ + h * 64 + 4 * tx] = o4;
      }
    }
    __syncthreads();

    // ---- W1 = W0 + U^T K ----
    {
      float acc[4][4] = {};
      #pragma unroll 8
      for (int t = 0; t < 64; ++t) {
        float xr[4], yc[4];
        #pragma unroll
        for (int r = 0; r < 4; ++r) xr[r] = Um[t][4 * ty + r];
        #pragma unroll
        for (int c = 0; c < 4; ++c) yc[c] = Kc[t][4 * tx + c];
        #pragma unroll
        for (int r = 0; r < 4; ++r)
          #pragma unroll
          for (int c = 0; c < 4; ++c) acc[r][c] = fmaf(xr[r], yc[c], acc[r][c]);
      }
      #pragma unroll
      for (int r = 0; r < 4; ++r)
        #pragma unroll
        for (int c = 0; c < 4; ++c) Wst[4 * ty + r][4 * tx + c] += acc[r][c];
    }
    __syncthreads();
  }
}

// ---------------------------------------------------------------------------
// [S,B,512] -> [B,S,512]
// ---------------------------------------------------------------------------
__global__ __launch_bounds__(128) void transpose_sb_to_bs(const float* __restrict__ in,
                                                          float* __restrict__ out)
{
  size_t m = blockIdx.x;            // s*B + b
  size_t s = m >> 3, b = m & 7;
  const float4* src = (const float4*)(in + m * HID_);
  float4* dst = (float4*)(out + (b * (size_t)S_ + s) * HID_);
  dst[threadIdx.x] = src[threadIdx.x];
}

// ---------------------------------------------------------------------------
extern "C" void kernel_launch(void* const* d_in, const int* in_sizes, int n_in,
                              void* d_out, int out_size, void* d_ws, size_t ws_size,
                              hipStream_t stream)
{
  const float* x        = (const float*)d_in[0];
  const float* ip_w     = (const float*)d_in[1];
  const float* ip_b     = (const float*)d_in[2];
  const float* fw_ln_g  = (const float*)d_in[3];
  const float* fw_ln_b  = (const float*)d_in[4];
  const float* fw_slow_w = (const float*)d_in[5];
  const float* fw_out_w  = (const float*)d_in[6];
  const float* ff_ln_g  = (const float*)d_in[7];
  const float* ff_ln_b  = (const float*)d_in[8];
  const float* ff_w1    = (const float*)d_in[9];
  const float* ff_b1    = (const float*)d_in[10];
  const float* ff_w2    = (const float*)d_in[11];
  const float* ff_b2    = (const float*)d_in[12];
  float* out = (float*)d_out;

  const int M = B_ * S_;  // 16384

  size_t need = ((size_t)M * HID_ + (size_t)M * (QKVB_ + HID_)) * sizeof(float);
  if (ws_size < need) return;

  float* cur  = (float*)d_ws;
  float* big  = cur + (size_t)M * HID_;
  float* qkvb = big;
  float* attn = big + (size_t)M * QKVB_;
  float* tmp  = out;  // LN scratch; fully overwritten by final transpose

  dim3 blk(256);

  gemm_bt<true, false, false, true><<<dim3(HID_ / 64, M / 64), blk, 0, stream>>>(
      x, ip_w, ip_b, nullptr, cur, M, HID_, HID_);

  for (int layer = 0; layer < 2; ++layer) {
    const float* sw = fw_slow_w + (size_t)layer * QKVB_ * HID_;
    const float* ow = fw_out_w  + (size_t)layer * HID_ * HID_;

    ln_k<<<M, 64, 0, stream>>>(cur, fw_ln_g + layer * HID_, fw_ln_b + layer * HID_, tmp);
    gemm_bt<false, false, false, false><<<dim3((QKVB_ + 63) / 64, M / 64), blk, 0, stream>>>(
        tmp, sw, nullptr, nullptr, qkvb, M, QKVB_, HID_);
    qkvb_transform<<<(size_t)M * H_, 64, 0, stream>>>(qkvb);
    delta_chunk<<<64, 256, 0, stream>>>(qkvb, attn);
    gemm_bt<false, false, true, false><<<dim3(HID_ / 64, M / 64), blk, 0, stream>>>(
        attn, ow, nullptr, cur, cur, M, HID_, HID_);

    if (layer == 0) {
      ln_k<<<M, 64, 0, stream>>>(cur, ff_ln_g, ff_ln_b, tmp);
      gemm_bt<true, true, false, false><<<dim3(FF_ / 64, M / 64), blk, 0, stream>>>(
          tmp, ff_w1, ff_b1, nullptr, big, M, FF_, HID_);
      gemm_bt<true, false, true, false><<<dim3(HID_ / 64, M / 64), blk, 0, stream>>>(
          big, ff_w2, ff_b2, cur, cur, M, HID_, FF_);
    }
  }

  transpose_sb_to_bs<<<M, 128, 0, stream>>>(cur, out);
}

// Round 3
// 3897.586 us; speedup vs baseline: 1.7351x; 1.0226x over previous
//
#include <hip/hip_runtime.h>
#include <hip/hip_bf16.h>

#define B_    8
#define S_    2048
#define HID_  512
#define H_    8
#define D_    64
#define FF_   2048
#define QKVB_ 1544   // H*(3*D+1) = 8*193
#define CPAD  65
#define NCH_  32     // S/64 chunks

// ---------------------------------------------------------------------------
// Generic tiled GEMM:  C[m,n] = epilogue( sum_k A[m,k] * W[n,k] )
// ---------------------------------------------------------------------------
template<bool BIAS, bool RELU, bool RES, bool ASWAP>
__global__ __launch_bounds__(256) void gemm_bt(
    const float* __restrict__ A, const float* __restrict__ Wt,
    const float* __restrict__ bias, const float* __restrict__ res,
    float* __restrict__ C, int M, int N, int K)
{
  __shared__ __align__(16) float As[16][68];
  __shared__ __align__(16) float Ws[16][68];
  const int bm = blockIdx.y * 64, bn = blockIdx.x * 64;
  const int tid = threadIdx.x;
  const int tx = tid & 15, ty = tid >> 4;
  const int lk = tid & 15, lr = tid >> 4;
  float acc[4][4] = {};

  for (int k0 = 0; k0 < K; k0 += 16) {
    #pragma unroll
    for (int rr = 0; rr < 4; ++rr) {
      int i = lr + rr * 16;
      int m = bm + i;
      int arow = ASWAP ? ((m & (B_ - 1)) * S_ + (m >> 3)) : m;
      As[lk][i] = A[(size_t)arow * K + k0 + lk];
    }
    #pragma unroll
    for (int rr = 0; rr < 4; ++rr) {
      int j = lr + rr * 16;
      int n = bn + j;
      Ws[lk][j] = (n < N) ? Wt[(size_t)n * K + k0 + lk] : 0.f;
    }
    __syncthreads();
    #pragma unroll
    for (int kk = 0; kk < 16; ++kk) {
      float4 av = *(const float4*)&As[kk][ty * 4];
      float4 wv = *(const float4*)&Ws[kk][tx * 4];
      float a4[4] = {av.x, av.y, av.z, av.w};
      float w4[4] = {wv.x, wv.y, wv.z, wv.w};
      #pragma unroll
      for (int a = 0; a < 4; ++a)
        #pragma unroll
        for (int b = 0; b < 4; ++b)
          acc[a][b] = fmaf(a4[a], w4[b], acc[a][b]);
    }
    __syncthreads();
  }

  #pragma unroll
  for (int a = 0; a < 4; ++a) {
    int m = bm + ty * 4 + a;
    #pragma unroll
    for (int b = 0; b < 4; ++b) {
      int n = bn + tx * 4 + b;
      if (n < N) {
        float v = acc[a][b];
        if (BIAS) v += bias[n];
        if (RES)  v += res[(size_t)m * N + n];
        if (RELU) v = fmaxf(v, 0.f);
        C[(size_t)m * N + n] = v;
      }
    }
  }
}

// ---------------------------------------------------------------------------
// LayerNorm over HID=512 per row; one wave per row.
// ---------------------------------------------------------------------------
__global__ __launch_bounds__(64) void ln_k(const float* __restrict__ x,
    const float* __restrict__ g, const float* __restrict__ bt,
    float* __restrict__ o)
{
  size_t row = blockIdx.x;
  int lane = threadIdx.x;
  const float4* xr = (const float4*)(x + row * HID_);
  float4 v0 = xr[lane];
  float4 v1 = xr[64 + lane];
  float s  = v0.x + v0.y + v0.z + v0.w + v1.x + v1.y + v1.z + v1.w;
  float ss = v0.x*v0.x + v0.y*v0.y + v0.z*v0.z + v0.w*v0.w
           + v1.x*v1.x + v1.y*v1.y + v1.z*v1.z + v1.w*v1.w;
  #pragma unroll
  for (int off = 32; off; off >>= 1) {
    s  += __shfl_xor(s, off);
    ss += __shfl_xor(ss, off);
  }
  float mean = s * (1.f / HID_);
  float inv  = rsqrtf(ss * (1.f / HID_) - mean * mean + 1e-5f);
  const float4* gv = (const float4*)g;
  const float4* bv = (const float4*)bt;
  float4 g0 = gv[lane], g1 = gv[64 + lane];
  float4 b0 = bv[lane], b1 = bv[64 + lane];
  float4 r0, r1;
  r0.x = (v0.x - mean) * inv * g0.x + b0.x;
  r0.y = (v0.y - mean) * inv * g0.y + b0.y;
  r0.z = (v0.z - mean) * inv * g0.z + b0.z;
  r0.w = (v0.w - mean) * inv * g0.w + b0.w;
  r1.x = (v1.x - mean) * inv * g1.x + b1.x;
  r1.y = (v1.y - mean) * inv * g1.y + b1.y;
  r1.z = (v1.z - mean) * inv * g1.z + b1.z;
  r1.w = (v1.w - mean) * inv * g1.w + b1.w;
  float4* ov = (float4*)(o + row * HID_);
  ov[lane] = r0;
  ov[64 + lane] = r1;
}

// ---------------------------------------------------------------------------
// In-place softmax(q), softmax(k), sigmoid(beta) per (s,b,h) row of qkvb.
// ---------------------------------------------------------------------------
__global__ __launch_bounds__(64) void qkvb_transform(float* __restrict__ qkvb)
{
  size_t r = blockIdx.x;
  float* base = qkvb + (r >> 3) * (size_t)QKVB_ + (r & 7) * 193;
  int lane = threadIdx.x;
  float q = base[lane], k = base[64 + lane];
  float mq = q, mk = k;
  #pragma unroll
  for (int off = 32; off; off >>= 1) {
    mq = fmaxf(mq, __shfl_xor(mq, off));
    mk = fmaxf(mk, __shfl_xor(mk, off));
  }
  float eq = __expf(q - mq), ek = __expf(k - mk);
  float sq = eq, sk = ek;
  #pragma unroll
  for (int off = 32; off; off >>= 1) { sq += __shfl_xor(sq, off); sk += __shfl_xor(sk, off); }
  base[lane]      = eq / sq;
  base[64 + lane] = ek / sk;
  if (lane == 0) { float bb = base[192]; base[192] = 1.f / (1.f + __expf(-bb)); }
}

// ---------------------------------------------------------------------------
// Delta rule, 3-phase chunked WY form.
// Per chunk j (64 steps), state W_j at entry:
//   A = strict_tril(diag(beta) K K^T), T = (I+A)^-1
//   U0 = T beta V ; CK = T beta K
//   M = CK^T K ; N = U0^T K            (phase 1, parallel over bh x chunk)
//   W_{j+1} = W_j (I - M_j) + N_j      (phase 2, serial over chunks)
//   U = T beta (V - K W_j^T) ; Out = Q W_j^T + tril(QK^T) U   (phase 3, parallel)
// ---------------------------------------------------------------------------
__global__ __launch_bounds__(256, 1) void delta_p1(const float* __restrict__ qkvb,
                                                   float* __restrict__ Mg,
                                                   float* __restrict__ Ng)
{
  __shared__ float Kc[64][CPAD];
  __shared__ float Am[64][CPAD];
  __shared__ float Uv[64][CPAD];
  __shared__ float Uk[64][CPAD];
  __shared__ float bet[64];
  const int id5 = blockIdx.x;           // bh*32 + j
  const int bh = id5 >> 5, j = id5 & 31;
  const int b = bh & 7, h = bh >> 3;
  const int t0 = j * 64;
  const int tid = threadIdx.x;
  const int tx = tid & 15, ty = tid >> 4;
  const int wid = tid >> 6, lane = tid & 63;
  const size_t hoff = (size_t)h * 193;

  #pragma unroll
  for (int i = 0; i < 16; ++i) {
    int idx = i * 256 + tid, row = idx >> 6, col = idx & 63;
    size_t gb = ((size_t)(t0 + row) * B_ + b) * QKVB_ + hoff;
    Kc[row][col] = qkvb[gb + 64 + col];
  }
  if (tid < 64) bet[tid] = qkvb[((size_t)(t0 + tid) * B_ + b) * QKVB_ + hoff + 192];
  __syncthreads();

  // rhs staging: Uv = beta*V (global), Uk = beta*K (LDS)
  #pragma unroll
  for (int i = 0; i < 16; ++i) {
    int idx = i * 256 + tid, row = idx >> 6, col = idx & 63;
    size_t gb = ((size_t)(t0 + row) * B_ + b) * QKVB_ + hoff;
    float bt_ = bet[row];
    Uv[row][col] = bt_ * qkvb[gb + 128 + col];
    Uk[row][col] = bt_ * Kc[row][col];
  }
  // A = beta ⊙ K K^T
  {
    float acc[4][4] = {};
    #pragma unroll 8
    for (int e = 0; e < 64; ++e) {
      float xr[4], yc[4];
      #pragma unroll
      for (int r = 0; r < 4; ++r) xr[r] = Kc[4 * ty + r][e];
      #pragma unroll
      for (int c = 0; c < 4; ++c) yc[c] = Kc[4 * tx + c][e];
      #pragma unroll
      for (int r = 0; r < 4; ++r)
        #pragma unroll
        for (int c = 0; c < 4; ++c) acc[r][c] = fmaf(xr[r], yc[c], acc[r][c]);
    }
    #pragma unroll
    for (int r = 0; r < 4; ++r) {
      float bt_ = bet[4 * ty + r];
      #pragma unroll
      for (int c = 0; c < 4; ++c) Am[4 * ty + r][4 * tx + c] = bt_ * acc[r][c];
    }
  }
  __syncthreads();

  // two-RHS blocked forward substitution: (I+A){U0,CK} = {beta V, beta K}
  #pragma unroll 1
  for (int blk = 0; blk < 4; ++blk) {
    if (wid == blk) {
      const int r0 = blk * 16;
      float uv[16], uk[16];
      #pragma unroll
      for (int i = 0; i < 16; ++i) { uv[i] = Uv[r0 + i][lane]; uk[i] = Uk[r0 + i][lane]; }
      #pragma unroll
      for (int jj = 0; jj < 15; ++jj) {
        #pragma unroll
        for (int t = jj + 1; t < 16; ++t) {
          float a = Am[r0 + t][r0 + jj];
          uv[t] = fmaf(-a, uv[jj], uv[t]);
          uk[t] = fmaf(-a, uk[jj], uk[t]);
        }
      }
      #pragma unroll
      for (int i = 0; i < 16; ++i) { Uv[r0 + i][lane] = uv[i]; Uk[r0 + i][lane] = uk[i]; }
    }
    __syncthreads();
    if (wid > blk) {
      const int r0 = blk * 16, rw = wid * 16;
      float uv[16], uk[16];
      #pragma unroll
      for (int i = 0; i < 16; ++i) { uv[i] = Uv[rw + i][lane]; uk[i] = Uk[rw + i][lane]; }
      #pragma unroll
      for (int jj = 0; jj < 16; ++jj) {
        float sv = Uv[r0 + jj][lane], sk = Uk[r0 + jj][lane];
        #pragma unroll
        for (int i = 0; i < 16; ++i) {
          float a = Am[rw + i][r0 + jj];
          uv[i] = fmaf(-a, sv, uv[i]);
          uk[i] = fmaf(-a, sk, uk[i]);
        }
      }
      #pragma unroll
      for (int i = 0; i < 16; ++i) { Uv[rw + i][lane] = uv[i]; Uk[rw + i][lane] = uk[i]; }
    }
    __syncthreads();
  }

  // M = CK^T K, N = U0^T K (fused over t)
  {
    float accM[4][4] = {}, accN[4][4] = {};
    #pragma unroll 4
    for (int t = 0; t < 64; ++t) {
      float xk[4], xv[4], yc[4];
      #pragma unroll
      for (int r = 0; r < 4; ++r) { xk[r] = Uk[t][4 * ty + r]; xv[r] = Uv[t][4 * ty + r]; }
      #pragma unroll
      for (int c = 0; c < 4; ++c) yc[c] = Kc[t][4 * tx + c];
      #pragma unroll
      for (int r = 0; r < 4; ++r)
        #pragma unroll
        for (int c = 0; c < 4; ++c) {
          accM[r][c] = fmaf(xk[r], yc[c], accM[r][c]);
          accN[r][c] = fmaf(xv[r], yc[c], accN[r][c]);
        }
    }
    size_t mb = (size_t)id5 * 4096;
    #pragma unroll
    for (int r = 0; r < 4; ++r) {
      *(float4*)&Mg[mb + (4 * ty + r) * 64 + 4 * tx] =
          make_float4(accM[r][0], accM[r][1], accM[r][2], accM[r][3]);
      *(float4*)&Ng[mb + (4 * ty + r) * 64 + 4 * tx] =
          make_float4(accN[r][0], accN[r][1], accN[r][2], accN[r][3]);
    }
  }
}

__global__ __launch_bounds__(256, 1) void delta_p2(const float* __restrict__ Mg,
                                                   const float* __restrict__ Ng,
                                                   float* __restrict__ Wg)
{
  __shared__ float Ws[64][CPAD];
  __shared__ float Ms[64][CPAD];
  __shared__ float Ns[64][CPAD];
  const int bh = blockIdx.x;
  const int tid = threadIdx.x;
  const int tx = tid & 15, ty = tid >> 4;
  for (int i = tid; i < 64 * CPAD; i += 256) (&Ws[0][0])[i] = 0.f;
  __syncthreads();

  for (int j = 0; j < NCH_; ++j) {
    size_t base = ((size_t)bh * NCH_ + j) * 4096;
    const float4* M4 = (const float4*)(Mg + base);
    const float4* N4 = (const float4*)(Ng + base);
    float4* W4 = (float4*)(Wg + base);
    #pragma unroll
    for (int i = 0; i < 4; ++i) {
      int idx4 = i * 256 + tid;
      int row = idx4 >> 4, c0 = (idx4 & 15) * 4;
      float4 m4 = M4[idx4];
      Ms[row][c0] = m4.x; Ms[row][c0 + 1] = m4.y; Ms[row][c0 + 2] = m4.z; Ms[row][c0 + 3] = m4.w;
      float4 n4 = N4[idx4];
      Ns[row][c0] = n4.x; Ns[row][c0 + 1] = n4.y; Ns[row][c0 + 2] = n4.z; Ns[row][c0 + 3] = n4.w;
      W4[idx4] = make_float4(Ws[row][c0], Ws[row][c0 + 1], Ws[row][c0 + 2], Ws[row][c0 + 3]);
    }
    __syncthreads();
    float acc[4][4] = {};
    #pragma unroll 8
    for (int e = 0; e < 64; ++e) {
      float xr[4], yc[4];
      #pragma unroll
      for (int r = 0; r < 4; ++r) xr[r] = Ws[4 * ty + r][e];
      #pragma unroll
      for (int c = 0; c < 4; ++c) yc[c] = Ms[e][4 * tx + c];
      #pragma unroll
      for (int r = 0; r < 4; ++r)
        #pragma unroll
        for (int c = 0; c < 4; ++c) acc[r][c] = fmaf(xr[r], yc[c], acc[r][c]);
    }
    __syncthreads();
    #pragma unroll
    for (int r = 0; r < 4; ++r)
      #pragma unroll
      for (int c = 0; c < 4; ++c)
        Ws[4 * ty + r][4 * tx + c] += Ns[4 * ty + r][4 * tx + c] - acc[r][c];
    __syncthreads();
  }
}

__global__ __launch_bounds__(256, 1) void delta_p3(const float* __restrict__ qkvb,
                                                   const float* __restrict__ Wg,
                                                   float* __restrict__ attn)
{
  __shared__ float Kc[64][CPAD];
  __shared__ float Qc[64][CPAD];
  __shared__ float Wb[64][CPAD];   // W_j, later reused for G
  __shared__ float Am[64][CPAD];
  __shared__ float Um[64][CPAD];
  __shared__ float bet[64];
  const int id5 = blockIdx.x;
  const int bh = id5 >> 5, j = id5 & 31;
  const int b = bh & 7, h = bh >> 3;
  const int t0 = j * 64;
  const int tid = threadIdx.x;
  const int tx = tid & 15, ty = tid >> 4;
  const int wid = tid >> 6, lane = tid & 63;
  const size_t hoff = (size_t)h * 193;

  #pragma unroll
  for (int i = 0; i < 16; ++i) {
    int idx = i * 256 + tid, row = idx >> 6, col = idx & 63;
    size_t gb = ((size_t)(t0 + row) * B_ + b) * QKVB_ + hoff;
    Qc[row][col] = qkvb[gb + col];
    Kc[row][col] = qkvb[gb + 64 + col];
  }
  {
    const float4* W4 = (const float4*)(Wg + (size_t)id5 * 4096);
    #pragma unroll
    for (int i = 0; i < 4; ++i) {
      int idx4 = i * 256 + tid;
      int row = idx4 >> 4, c0 = (idx4 & 15) * 4;
      float4 w4 = W4[idx4];
      Wb[row][c0] = w4.x; Wb[row][c0 + 1] = w4.y; Wb[row][c0 + 2] = w4.z; Wb[row][c0 + 3] = w4.w;
    }
  }
  if (tid < 64) bet[tid] = qkvb[((size_t)(t0 + tid) * B_ + b) * QKVB_ + hoff + 192];
  __syncthreads();

  // kw = K W^T, qw = Q W^T (fused; W reads shared)
  float kw[4][4] = {}, qw[4][4] = {};
  #pragma unroll 4
  for (int e = 0; e < 64; ++e) {
    float k4[4], q4[4], w4[4];
    #pragma unroll
    for (int r = 0; r < 4; ++r) { k4[r] = Kc[4 * ty + r][e]; q4[r] = Qc[4 * ty + r][e]; }
    #pragma unroll
    for (int c = 0; c < 4; ++c) w4[c] = Wb[4 * tx + c][e];
    #pragma unroll
    for (int r = 0; r < 4; ++r)
      #pragma unroll
      for (int c = 0; c < 4; ++c) {
        kw[r][c] = fmaf(k4[r], w4[c], kw[r][c]);
        qw[r][c] = fmaf(q4[r], w4[c], qw[r][c]);
      }
  }
  // A = beta ⊙ K K^T
  {
    float acc[4][4] = {};
    #pragma unroll 8
    for (int e = 0; e < 64; ++e) {
      float xr[4], yc[4];
      #pragma unroll
      for (int r = 0; r < 4; ++r) xr[r] = Kc[4 * ty + r][e];
      #pragma unroll
      for (int c = 0; c < 4; ++c) yc[c] = Kc[4 * tx + c][e];
      #pragma unroll
      for (int r = 0; r < 4; ++r)
        #pragma unroll
        for (int c = 0; c < 4; ++c) acc[r][c] = fmaf(xr[r], yc[c], acc[r][c]);
    }
    #pragma unroll
    for (int r = 0; r < 4; ++r) {
      float bt_ = bet[4 * ty + r];
      #pragma unroll
      for (int c = 0; c < 4; ++c) Am[4 * ty + r][4 * tx + c] = bt_ * acc[r][c];
    }
  }
  // rhs: Um = beta (V - K W^T)
  #pragma unroll
  for (int r = 0; r < 4; ++r) {
    size_t gb = ((size_t)(t0 + 4 * ty + r) * B_ + b) * QKVB_ + hoff + 128;
    float bt_ = bet[4 * ty + r];
    #pragma unroll
    for (int c = 0; c < 4; ++c) {
      float v = qkvb[gb + 4 * tx + c];
      Um[4 * ty + r][4 * tx + c] = bt_ * (v - kw[r][c]);
    }
  }
  __syncthreads();

  // forward substitution (single RHS)
  #pragma unroll 1
  for (int blk = 0; blk < 4; ++blk) {
    if (wid == blk) {
      const int r0 = blk * 16;
      float u[16];
      #pragma unroll
      for (int i = 0; i < 16; ++i) u[i] = Um[r0 + i][lane];
      #pragma unroll
      for (int jj = 0; jj < 15; ++jj) {
        float uj = u[jj];
        #pragma unroll
        for (int t = jj + 1; t < 16; ++t)
          u[t] = fmaf(-Am[r0 + t][r0 + jj], uj, u[t]);
      }
      #pragma unroll
      for (int i = 0; i < 16; ++i) Um[r0 + i][lane] = u[i];
    }
    __syncthreads();
    if (wid > blk) {
      const int r0 = blk * 16, rw = wid * 16;
      float u[16];
      #pragma unroll
      for (int i = 0; i < 16; ++i) u[i] = Um[rw + i][lane];
      #pragma unroll
      for (int jj = 0; jj < 16; ++jj) {
        float uj = Um[r0 + jj][lane];
        #pragma unroll
        for (int i = 0; i < 16; ++i)
          u[i] = fmaf(-Am[rw + i][r0 + jj], uj, u[i]);
      }
      #pragma unroll
      for (int i = 0; i < 16; ++i) Um[rw + i][lane] = u[i];
    }
    __syncthreads();
  }

  // G = tril(Q K^T) into Wb (W dead)
  {
    float acc[4][4] = {};
    #pragma unroll 8
    for (int e = 0; e < 64; ++e) {
      float xr[4], yc[4];
      #pragma unroll
      for (int r = 0; r < 4; ++r) xr[r] = Qc[4 * ty + r][e];
      #pragma unroll
      for (int c = 0; c < 4; ++c) yc[c] = Kc[4 * tx + c][e];
      #pragma unroll
      for (int r = 0; r < 4; ++r)
        #pragma unroll
        for (int c = 0; c < 4; ++c) acc[r][c] = fmaf(xr[r], yc[c], acc[r][c]);
    }
    #pragma unroll
    for (int r = 0; r < 4; ++r)
      #pragma unroll
      for (int c = 0; c < 4; ++c)
        Wb[4 * ty + r][4 * tx + c] = (4 * tx + c <= 4 * ty + r) ? acc[r][c] : 0.f;
  }
  __syncthreads();

  // Out = qw + G U
  {
    float acc[4][4];
    #pragma unroll
    for (int r = 0; r < 4; ++r)
      #pragma unroll
      for (int c = 0; c < 4; ++c) acc[r][c] = qw[r][c];
    #pragma unroll 8
    for (int t = 0; t < 64; ++t) {
      float xr[4], yc[4];
      #pragma unroll
      for (int r = 0; r < 4; ++r) xr[r] = Wb[4 * ty + r][t];
      #pragma unroll
      for (int c = 0; c < 4; ++c) yc[c] = Um[t][4 * tx + c];
      #pragma unroll
      for (int r = 0; r < 4; ++r)
        #pragma unroll
        for (int c = 0; c < 4; ++c) acc[r][c] = fmaf(xr[r], yc[c], acc[r][c]);
    }
    #pragma unroll
    for (int r = 0; r < 4; ++r)
      *(float4*)&attn[((size_t)(t0 + 4 * ty + r) * B_ + b) * HID_ + h * 64 + 4 * tx] =
          make_float4(acc[r][0], acc[r][1], acc[r][2], acc[r][3]);
  }
}

// ---------------------------------------------------------------------------
// Fallback: single-kernel chunked scan (round-1 version, used if ws too small)
// ---------------------------------------------------------------------------
__global__ __launch_bounds__(256, 1) void delta_chunk(const float* __restrict__ qkvb,
                                                      float* __restrict__ attn)
{
  __shared__ float Wst[64][CPAD];
  __shared__ float Kc [64][CPAD];
  __shared__ float Qc [64][CPAD];
  __shared__ float Am [64][CPAD];
  __shared__ float Um [64][CPAD];
  __shared__ float bet[64];

  const int p = blockIdx.x;
  const int b = p & 7, h = p >> 3;
  const int tid = threadIdx.x;
  const int tx = tid & 15, ty = tid >> 4;
  const int wid = tid >> 6, lane = tid & 63;
  const size_t hoff = (size_t)h * 193;

  for (int i = tid; i < 64 * CPAD; i += 256) (&Wst[0][0])[i] = 0.f;
  __syncthreads();

  for (int t0 = 0; t0 < S_; t0 += 64) {
    #pragma unroll
    for (int i = 0; i < 16; ++i) {
      int id = i * 256 + tid, row = id >> 6, col = id & 63;
      size_t gb = ((size_t)(t0 + row) * B_ + b) * QKVB_ + hoff;
      Qc[row][col] = qkvb[gb + col];
      Kc[row][col] = qkvb[gb + 64 + col];
    }
    if (tid < 64) bet[tid] = qkvb[((size_t)(t0 + tid) * B_ + b) * QKVB_ + hoff + 192];
    __syncthreads();
    {
      float acc[4][4] = {};
      #pragma unroll 8
      for (int e = 0; e < 64; ++e) {
        float xr[4], yc[4];
        #pragma unroll
        for (int r = 0; r < 4; ++r) xr[r] = Kc[4 * ty + r][e];
        #pragma unroll
        for (int c = 0; c < 4; ++c) yc[c] = Kc[4 * tx + c][e];
        #pragma unroll
        for (int r = 0; r < 4; ++r)
          #pragma unroll
          for (int c = 0; c < 4; ++c) acc[r][c] = fmaf(xr[r], yc[c], acc[r][c]);
      }
      #pragma unroll
      for (int r = 0; r < 4; ++r) {
        float bt_ = bet[4 * ty + r];
        #pragma unroll
        for (int c = 0; c < 4; ++c) Am[4 * ty + r][4 * tx + c] = bt_ * acc[r][c];
      }
    }
    {
      float acc[4][4] = {};
      #pragma unroll 8
      for (int e = 0; e < 64; ++e) {
        float xr[4], yc[4];
        #pragma unroll
        for (int r = 0; r < 4; ++r) xr[r] = Kc[4 * ty + r][e];
        #pragma unroll
        for (int c = 0; c < 4; ++c) yc[c] = Wst[4 * tx + c][e];
        #pragma unroll
        for (int r = 0; r < 4; ++r)
          #pragma unroll
          for (int c = 0; c < 4; ++c) acc[r][c] = fmaf(xr[r], yc[c], acc[r][c]);
      }
      #pragma unroll
      for (int r = 0; r < 4; ++r) {
        float bt_ = bet[4 * ty + r];
        size_t gb = ((size_t)(t0 + 4 * ty + r) * B_ + b) * QKVB_ + hoff + 128;
        #pragma unroll
        for (int c = 0; c < 4; ++c) {
          float v = qkvb[gb + 4 * tx + c];
          Um[4 * ty + r][4 * tx + c] = bt_ * (v - acc[r][c]);
        }
      }
    }
    __syncthreads();
    #pragma unroll 1
    for (int blk = 0; blk < 4; ++blk) {
      if (wid == blk) {
        const int r0 = blk * 16;
        float u[16];
        #pragma unroll
        for (int i = 0; i < 16; ++i) u[i] = Um[r0 + i][lane];
        #pragma unroll
        for (int jj = 0; jj < 15; ++jj) {
          float uj = u[jj];
          #pragma unroll
          for (int t = jj + 1; t < 16; ++t)
            u[t] = fmaf(-Am[r0 + t][r0 + jj], uj, u[t]);
        }
        #pragma unroll
        for (int i = 0; i < 16; ++i) Um[r0 + i][lane] = u[i];
      }
      __syncthreads();
      if (wid > blk) {
        const int r0 = blk * 16, rw = wid * 16;
        float u[16];
        #pragma unroll
        for (int i = 0; i < 16; ++i) u[i] = Um[rw + i][lane];
        #pragma unroll
        for (int jj = 0; jj < 16; ++jj) {
          float uj = Um[r0 + jj][lane];
          #pragma unroll
          for (int i = 0; i < 16; ++i)
            u[i] = fmaf(-Am[rw + i][r0 + jj], uj, u[i]);
        }
        #pragma unroll
        for (int i = 0; i < 16; ++i) Um[rw + i][lane] = u[i];
      }
      __syncthreads();
    }
    {
      float acc[4][4] = {};
      #pragma unroll 8
      for (int e = 0; e < 64; ++e) {
        float xr[4], yc[4];
        #pragma unroll
        for (int r = 0; r < 4; ++r) xr[r] = Qc[4 * ty + r][e];
        #pragma unroll
        for (int c = 0; c < 4; ++c) yc[c] = Kc[4 * tx + c][e];
        #pragma unroll
        for (int r = 0; r < 4; ++r)
          #pragma unroll
          for (int c = 0; c < 4; ++c) acc[r][c] = fmaf(xr[r], yc[c], acc[r][c]);
      }
      __syncthreads();
      #pragma unroll
      for (int r = 0; r < 4; ++r)
        #pragma unroll
        for (int c = 0; c < 4; ++c)
          Am[4 * ty + r][4 * tx + c] = (4 * tx + c <= 4 * ty + r) ? acc[r][c] : 0.f;
    }
    __syncthreads();
    {
      float acc[4][4] = {};
      #pragma unroll 8
      for (int e = 0; e < 64; ++e) {
        float xr[4], yc[4];
        #pragma unroll
        for (int r = 0; r < 4; ++r) xr[r] = Qc[4 * ty + r][e];
        #pragma unroll
        for (int c = 0; c < 4; ++c) yc[c] = Wst[4 * tx + c][e];
        #pragma unroll
        for (int r = 0; r < 4; ++r)
          #pragma unroll
          for (int c = 0; c < 4; ++c) acc[r][c] = fmaf(xr[r], yc[c], acc[r][c]);
      }
      #pragma unroll 8
      for (int jj = 0; jj < 64; ++jj) {
        float xr[4], yc[4];
        #pragma unroll
        for (int r = 0; r < 4; ++r) xr[r] = Am[4 * ty + r][jj];
        #pragma unroll
        for (int c = 0; c < 4; ++c) yc[c] = Um[jj][4 * tx + c];
        #pragma unroll
        for (int r = 0; r < 4; ++r)
          #pragma unroll
          for (int c = 0; c < 4; ++c) acc[r][c] = fmaf(xr[r], yc[c], acc[r][c]);
      }
      #pragma unroll
      for (int r = 0; r < 4; ++r)
        *(float4*)&attn[((size_t)(t0 + 4 * ty + r) * B_ + b) * HID_ + h * 64 + 4 * tx] =
            make_float4(acc[r][0], acc[r][1], acc[r][2], acc[r][3]);
    }
    __syncthreads();
    {
      float acc[4][4] = {};
      #pragma unroll 8
      for (int t = 0; t < 64; ++t) {
        float xr[4], yc[4];
        #pragma unroll
        for (int r = 0; r < 4; ++r) xr[r] = Um[t][4 * ty + r];
        #pragma unroll
        for (int c = 0; c < 4; ++c) yc[c] = Kc[t][4 * tx + c];
        #pragma unroll
        for (int r = 0; r < 4; ++r)
          #pragma unroll
          for (int c = 0; c < 4; ++c) acc[r][c] = fmaf(xr[r], yc[c], acc[r][c]);
      }
      #pragma unroll
      for (int r = 0; r < 4; ++r)
        #pragma unroll
        for (int c = 0; c < 4; ++c) Wst[4 * ty + r][4 * tx + c] += acc[r][c];
    }
    __syncthreads();
  }
}

// ---------------------------------------------------------------------------
__global__ __launch_bounds__(128) void transpose_sb_to_bs(const float* __restrict__ in,
                                                          float* __restrict__ out)
{
  size_t m = blockIdx.x;
  size_t s = m >> 3, b = m & 7;
  const float4* src = (const float4*)(in + m * HID_);
  float4* dst = (float4*)(out + (b * (size_t)S_ + s) * HID_);
  dst[threadIdx.x] = src[threadIdx.x];
}

// ---------------------------------------------------------------------------
extern "C" void kernel_launch(void* const* d_in, const int* in_sizes, int n_in,
                              void* d_out, int out_size, void* d_ws, size_t ws_size,
                              hipStream_t stream)
{
  const float* x        = (const float*)d_in[0];
  const float* ip_w     = (const float*)d_in[1];
  const float* ip_b     = (const float*)d_in[2];
  const float* fw_ln_g  = (const float*)d_in[3];
  const float* fw_ln_b  = (const float*)d_in[4];
  const float* fw_slow_w = (const float*)d_in[5];
  const float* fw_out_w  = (const float*)d_in[6];
  const float* ff_ln_g  = (const float*)d_in[7];
  const float* ff_ln_b  = (const float*)d_in[8];
  const float* ff_w1    = (const float*)d_in[9];
  const float* ff_b1    = (const float*)d_in[10];
  const float* ff_w2    = (const float*)d_in[11];
  const float* ff_b2    = (const float*)d_in[12];
  float* out = (float*)d_out;

  const int M = B_ * S_;  // 16384
  const size_t matN = (size_t)64 * NCH_ * 4096;  // 8.4M floats per matrix

  size_t need_old = ((size_t)M * (HID_ + QKVB_ + HID_)) * sizeof(float);
  size_t need_new = need_old + 3 * matN * sizeof(float);
  if (ws_size < need_old) return;
  const bool three_phase = (ws_size >= need_new);

  float* cur  = (float*)d_ws;
  float* qkvb = cur + (size_t)M * HID_;
  float* attn = qkvb + (size_t)M * QKVB_;
  float* Mg   = attn + (size_t)M * HID_;
  float* Ng   = Mg + matN;
  float* Wg   = Ng + matN;
  float* big  = qkvb;     // FFN hidden aliases qkvb+attn region
  float* tmp  = out;      // LN scratch; fully overwritten by final transpose

  dim3 blk(256);

  gemm_bt<true, false, false, true><<<dim3(HID_ / 64, M / 64), blk, 0, stream>>>(
      x, ip_w, ip_b, nullptr, cur, M, HID_, HID_);

  for (int layer = 0; layer < 2; ++layer) {
    const float* sw = fw_slow_w + (size_t)layer * QKVB_ * HID_;
    const float* ow = fw_out_w  + (size_t)layer * HID_ * HID_;

    ln_k<<<M, 64, 0, stream>>>(cur, fw_ln_g + layer * HID_, fw_ln_b + layer * HID_, tmp);
    gemm_bt<false, false, false, false><<<dim3((QKVB_ + 63) / 64, M / 64), blk, 0, stream>>>(
        tmp, sw, nullptr, nullptr, qkvb, M, QKVB_, HID_);
    qkvb_transform<<<(size_t)M * H_, 64, 0, stream>>>(qkvb);
    if (three_phase) {
      delta_p1<<<64 * NCH_, 256, 0, stream>>>(qkvb, Mg, Ng);
      delta_p2<<<64, 256, 0, stream>>>(Mg, Ng, Wg);
      delta_p3<<<64 * NCH_, 256, 0, stream>>>(qkvb, Wg, attn);
    } else {
      delta_chunk<<<64, 256, 0, stream>>>(qkvb, attn);
    }
    gemm_bt<false, false, true, false><<<dim3(HID_ / 64, M / 64), blk, 0, stream>>>(
        attn, ow, nullptr, cur, cur, M, HID_, HID_);

    if (layer == 0) {
      ln_k<<<M, 64, 0, stream>>>(cur, ff_ln_g, ff_ln_b, tmp);
      gemm_bt<true, true, false, false><<<dim3(FF_ / 64, M / 64), blk, 0, stream>>>(
          tmp, ff_w1, ff_b1, nullptr, big, M, FF_, HID_);
      gemm_bt<true, false, true, false><<<dim3(HID_ / 64, M / 64), blk, 0, stream>>>(
          big, ff_w2, ff_b2, cur, cur, M, HID_, FF_);
    }
  }

  transpose_sb_to_bs<<<M, 128, 0, stream>>>(cur, out);
}

// Round 4
// 1448.738 us; speedup vs baseline: 4.6681x; 2.6903x over previous
//
#include <hip/hip_runtime.h>
#include <hip/hip_bf16.h>

#define B_    8
#define S_    2048
#define HID_  512
#define H_    8
#define D_    64
#define FF_   2048
#define QKVB_ 1544   // H*(3*D+1) = 8*193
#define CPAD  65
#define NCH_  32     // S/64 chunks

typedef unsigned short u16;
typedef __attribute__((ext_vector_type(8))) short short8;
typedef __attribute__((ext_vector_type(4))) float f32x4;

__device__ __forceinline__ u16 f2bf(float x) {           // RNE fp32->bf16
  unsigned u = __builtin_bit_cast(unsigned, x);
  unsigned r = (u + 0x7FFFu + ((u >> 16) & 1u)) >> 16;
  return (u16)r;
}
__device__ __forceinline__ float bf2f(u16 v) {
  return __builtin_bit_cast(float, (unsigned)v << 16);
}

// ---------------------------------------------------------------------------
// bf16 MFMA GEMM:  C[m,n] = epilogue( sum_k A[m,k] * W[n,k] ), A/W fp32 in HBM,
// converted to bf16 during LDS staging. 128x128 tile, BK=32, 4 waves (2x2),
// each wave 64x64 via 4x4 frags of mfma_f32_16x16x32_bf16.
// LDS row stride 40 bf16 (80B) -> <=2-way bank aliasing (free).
// ---------------------------------------------------------------------------
template<bool BIAS, bool RELU, bool RES, bool ASWAP>
__global__ __launch_bounds__(256) void gemm_mfma(
    const float* __restrict__ A, const float* __restrict__ Wt,
    const float* __restrict__ bias, const float* __restrict__ res,
    float* __restrict__ C, int M, int N, int K)
{
  __shared__ u16 As[128 * 40];
  __shared__ u16 Bs[128 * 40];
  const int tid = threadIdx.x;
  const int bm = blockIdx.y * 128, bn = blockIdx.x * 128;
  const int wave = tid >> 6, lane = tid & 63;
  const int wr = wave >> 1, wc = wave & 1;
  const int row16 = lane & 15, kg = lane >> 4;
  const int srow = tid >> 1, sh = tid & 1;   // staging: row 0..127, 16-float half

  f32x4 acc[4][4] = {};

  const int ktiles = K >> 5;
  for (int kt = 0; kt < ktiles; ++kt) {
    const int k0 = kt << 5;
    float4 av[4], wv[4];
    {
      int am = bm + srow;
      int garow = ASWAP ? ((am & 7) * S_ + (am >> 3)) : am;
      const float4* ap = (const float4*)(A + (size_t)garow * K + k0 + sh * 16);
      av[0] = ap[0]; av[1] = ap[1]; av[2] = ap[2]; av[3] = ap[3];
      int wn = bn + srow;
      if (wn < N) {
        const float4* wp = (const float4*)(Wt + (size_t)wn * K + k0 + sh * 16);
        wv[0] = wp[0]; wv[1] = wp[1]; wv[2] = wp[2]; wv[3] = wp[3];
      } else {
        wv[0] = wv[1] = wv[2] = wv[3] = make_float4(0.f, 0.f, 0.f, 0.f);
      }
    }
    __syncthreads();   // previous iteration's fragment reads complete
    {
      union { u16 u[16]; short8 s[2]; } pa, pw;
      #pragma unroll
      for (int v = 0; v < 4; ++v) {
        const float4 a4 = av[v], w4 = wv[v];
        pa.u[v * 4 + 0] = f2bf(a4.x); pa.u[v * 4 + 1] = f2bf(a4.y);
        pa.u[v * 4 + 2] = f2bf(a4.z); pa.u[v * 4 + 3] = f2bf(a4.w);
        pw.u[v * 4 + 0] = f2bf(w4.x); pw.u[v * 4 + 1] = f2bf(w4.y);
        pw.u[v * 4 + 2] = f2bf(w4.z); pw.u[v * 4 + 3] = f2bf(w4.w);
      }
      *(short8*)&As[srow * 40 + sh * 16]     = pa.s[0];
      *(short8*)&As[srow * 40 + sh * 16 + 8] = pa.s[1];
      *(short8*)&Bs[srow * 40 + sh * 16]     = pw.s[0];
      *(short8*)&Bs[srow * 40 + sh * 16 + 8] = pw.s[1];
    }
    __syncthreads();
    short8 af[4], bf[4];
    #pragma unroll
    for (int m = 0; m < 4; ++m)
      af[m] = *(const short8*)&As[(wr * 64 + m * 16 + row16) * 40 + kg * 8];
    #pragma unroll
    for (int n = 0; n < 4; ++n)
      bf[n] = *(const short8*)&Bs[(wc * 64 + n * 16 + row16) * 40 + kg * 8];
    #pragma unroll
    for (int m = 0; m < 4; ++m)
      #pragma unroll
      for (int n = 0; n < 4; ++n)
        acc[m][n] = __builtin_amdgcn_mfma_f32_16x16x32_bf16(af[m], bf[n], acc[m][n], 0, 0, 0);
  }

  // epilogue: C/D frag mapping col=lane&15, row=(lane>>4)*4+reg
  #pragma unroll
  for (int m = 0; m < 4; ++m) {
    #pragma unroll
    for (int n = 0; n < 4; ++n) {
      const int gcol = bn + wc * 64 + n * 16 + row16;
      if (gcol < N) {
        #pragma unroll
        for (int j = 0; j < 4; ++j) {
          const int grow = bm + wr * 64 + m * 16 + kg * 4 + j;
          float v = acc[m][n][j];
          if (BIAS) v += bias[gcol];
          if (RES)  v += res[(size_t)grow * N + gcol];
          if (RELU) v = fmaxf(v, 0.f);
          C[(size_t)grow * N + gcol] = v;
        }
      }
    }
  }
}

// ---------------------------------------------------------------------------
// LayerNorm over HID=512 per row; one wave per row.
// ---------------------------------------------------------------------------
__global__ __launch_bounds__(64) void ln_k(const float* __restrict__ x,
    const float* __restrict__ g, const float* __restrict__ bt,
    float* __restrict__ o)
{
  size_t row = blockIdx.x;
  int lane = threadIdx.x;
  const float4* xr = (const float4*)(x + row * HID_);
  float4 v0 = xr[lane];
  float4 v1 = xr[64 + lane];
  float s  = v0.x + v0.y + v0.z + v0.w + v1.x + v1.y + v1.z + v1.w;
  float ss = v0.x*v0.x + v0.y*v0.y + v0.z*v0.z + v0.w*v0.w
           + v1.x*v1.x + v1.y*v1.y + v1.z*v1.z + v1.w*v1.w;
  #pragma unroll
  for (int off = 32; off; off >>= 1) {
    s  += __shfl_xor(s, off);
    ss += __shfl_xor(ss, off);
  }
  float mean = s * (1.f / HID_);
  float inv  = rsqrtf(ss * (1.f / HID_) - mean * mean + 1e-5f);
  const float4* gv = (const float4*)g;
  const float4* bv = (const float4*)bt;
  float4 g0 = gv[lane], g1 = gv[64 + lane];
  float4 b0 = bv[lane], b1 = bv[64 + lane];
  float4 r0, r1;
  r0.x = (v0.x - mean) * inv * g0.x + b0.x;
  r0.y = (v0.y - mean) * inv * g0.y + b0.y;
  r0.z = (v0.z - mean) * inv * g0.z + b0.z;
  r0.w = (v0.w - mean) * inv * g0.w + b0.w;
  r1.x = (v1.x - mean) * inv * g1.x + b1.x;
  r1.y = (v1.y - mean) * inv * g1.y + b1.y;
  r1.z = (v1.z - mean) * inv * g1.z + b1.z;
  r1.w = (v1.w - mean) * inv * g1.w + b1.w;
  float4* ov = (float4*)(o + row * HID_);
  ov[lane] = r0;
  ov[64 + lane] = r1;
}

// ---------------------------------------------------------------------------
// In-place softmax(q), softmax(k), sigmoid(beta) per (s,b,h) row of qkvb.
// ---------------------------------------------------------------------------
__global__ __launch_bounds__(64) void qkvb_transform(float* __restrict__ qkvb)
{
  size_t r = blockIdx.x;
  float* base = qkvb + (r >> 3) * (size_t)QKVB_ + (r & 7) * 193;
  int lane = threadIdx.x;
  float q = base[lane], k = base[64 + lane];
  float mq = q, mk = k;
  #pragma unroll
  for (int off = 32; off; off >>= 1) {
    mq = fmaxf(mq, __shfl_xor(mq, off));
    mk = fmaxf(mk, __shfl_xor(mk, off));
  }
  float eq = __expf(q - mq), ek = __expf(k - mk);
  float sq = eq, sk = ek;
  #pragma unroll
  for (int off = 32; off; off >>= 1) { sq += __shfl_xor(sq, off); sk += __shfl_xor(sk, off); }
  base[lane]      = eq / sq;
  base[64 + lane] = ek / sk;
  if (lane == 0) { float bb = base[192]; base[192] = 1.f / (1.f + __expf(-bb)); }
}

// ---------------------------------------------------------------------------
// Delta rule, 3-phase chunked WY form.
//   A = strict_tril(diag(beta) K K^T), T = (I+A)^-1
//   U0 = T beta V ; CK = T beta K
//   M = CK^T K ; N = U0^T K            (phase 1, parallel; M,N stored bf16)
//   W_{j+1} = W_j (I - M_j) + N_j      (phase 2, serial over chunks; W fp32)
//   U = T beta (V - K W_j^T) ; Out = Q W_j^T + tril(QK^T) U   (phase 3)
// ---------------------------------------------------------------------------
__global__ __launch_bounds__(256, 1) void delta_p1(const float* __restrict__ qkvb,
                                                   u16* __restrict__ Mg,
                                                   u16* __restrict__ Ng)
{
  __shared__ float Kc[64][CPAD];
  __shared__ float Am[64][CPAD];
  __shared__ float Uv[64][CPAD];
  __shared__ float Uk[64][CPAD];
  __shared__ float bet[64];
  const int id5 = blockIdx.x;           // bh*32 + j
  const int bh = id5 >> 5;
  const int b = bh & 7, h = bh >> 3;
  const int t0 = (id5 & 31) * 64;
  const int tid = threadIdx.x;
  const int tx = tid & 15, ty = tid >> 4;
  const int wid = tid >> 6, lane = tid & 63;
  const size_t hoff = (size_t)h * 193;

  #pragma unroll
  for (int i = 0; i < 16; ++i) {
    int idx = i * 256 + tid, row = idx >> 6, col = idx & 63;
    size_t gb = ((size_t)(t0 + row) * B_ + b) * QKVB_ + hoff;
    Kc[row][col] = qkvb[gb + 64 + col];
  }
  if (tid < 64) bet[tid] = qkvb[((size_t)(t0 + tid) * B_ + b) * QKVB_ + hoff + 192];
  __syncthreads();

  #pragma unroll
  for (int i = 0; i < 16; ++i) {
    int idx = i * 256 + tid, row = idx >> 6, col = idx & 63;
    size_t gb = ((size_t)(t0 + row) * B_ + b) * QKVB_ + hoff;
    float bt_ = bet[row];
    Uv[row][col] = bt_ * qkvb[gb + 128 + col];
    Uk[row][col] = bt_ * Kc[row][col];
  }
  {
    float acc[4][4] = {};
    #pragma unroll 8
    for (int e = 0; e < 64; ++e) {
      float xr[4], yc[4];
      #pragma unroll
      for (int r = 0; r < 4; ++r) xr[r] = Kc[4 * ty + r][e];
      #pragma unroll
      for (int c = 0; c < 4; ++c) yc[c] = Kc[4 * tx + c][e];
      #pragma unroll
      for (int r = 0; r < 4; ++r)
        #pragma unroll
        for (int c = 0; c < 4; ++c) acc[r][c] = fmaf(xr[r], yc[c], acc[r][c]);
    }
    #pragma unroll
    for (int r = 0; r < 4; ++r) {
      float bt_ = bet[4 * ty + r];
      #pragma unroll
      for (int c = 0; c < 4; ++c) Am[4 * ty + r][4 * tx + c] = bt_ * acc[r][c];
    }
  }
  __syncthreads();

  // two-RHS blocked forward substitution: (I+A){U0,CK} = {beta V, beta K}
  #pragma unroll 1
  for (int blk = 0; blk < 4; ++blk) {
    if (wid == blk) {
      const int r0 = blk * 16;
      float uv[16], uk[16];
      #pragma unroll
      for (int i = 0; i < 16; ++i) { uv[i] = Uv[r0 + i][lane]; uk[i] = Uk[r0 + i][lane]; }
      #pragma unroll
      for (int jj = 0; jj < 15; ++jj) {
        #pragma unroll
        for (int t = jj + 1; t < 16; ++t) {
          float a = Am[r0 + t][r0 + jj];
          uv[t] = fmaf(-a, uv[jj], uv[t]);
          uk[t] = fmaf(-a, uk[jj], uk[t]);
        }
      }
      #pragma unroll
      for (int i = 0; i < 16; ++i) { Uv[r0 + i][lane] = uv[i]; Uk[r0 + i][lane] = uk[i]; }
    }
    __syncthreads();
    if (wid > blk) {
      const int r0 = blk * 16, rw = wid * 16;
      float uv[16], uk[16];
      #pragma unroll
      for (int i = 0; i < 16; ++i) { uv[i] = Uv[rw + i][lane]; uk[i] = Uk[rw + i][lane]; }
      #pragma unroll
      for (int jj = 0; jj < 16; ++jj) {
        float sv = Uv[r0 + jj][lane], sk = Uk[r0 + jj][lane];
        #pragma unroll
        for (int i = 0; i < 16; ++i) {
          float a = Am[rw + i][r0 + jj];
          uv[i] = fmaf(-a, sv, uv[i]);
          uk[i] = fmaf(-a, sk, uk[i]);
        }
      }
      #pragma unroll
      for (int i = 0; i < 16; ++i) { Uv[rw + i][lane] = uv[i]; Uk[rw + i][lane] = uk[i]; }
    }
    __syncthreads();
  }

  // M = CK^T K, N = U0^T K; store bf16
  {
    float accM[4][4] = {}, accN[4][4] = {};
    #pragma unroll 4
    for (int t = 0; t < 64; ++t) {
      float xk[4], xv[4], yc[4];
      #pragma unroll
      for (int r = 0; r < 4; ++r) { xk[r] = Uk[t][4 * ty + r]; xv[r] = Uv[t][4 * ty + r]; }
      #pragma unroll
      for (int c = 0; c < 4; ++c) yc[c] = Kc[t][4 * tx + c];
      #pragma unroll
      for (int r = 0; r < 4; ++r)
        #pragma unroll
        for (int c = 0; c < 4; ++c) {
          accM[r][c] = fmaf(xk[r], yc[c], accM[r][c]);
          accN[r][c] = fmaf(xv[r], yc[c], accN[r][c]);
        }
    }
    size_t mb = (size_t)id5 * 4096;
    #pragma unroll
    for (int r = 0; r < 4; ++r) {
      uint2 pm, pn;
      pm.x = (unsigned)f2bf(accM[r][0]) | ((unsigned)f2bf(accM[r][1]) << 16);
      pm.y = (unsigned)f2bf(accM[r][2]) | ((unsigned)f2bf(accM[r][3]) << 16);
      pn.x = (unsigned)f2bf(accN[r][0]) | ((unsigned)f2bf(accN[r][1]) << 16);
      pn.y = (unsigned)f2bf(accN[r][2]) | ((unsigned)f2bf(accN[r][3]) << 16);
      *(uint2*)&Mg[mb + (4 * ty + r) * 64 + 4 * tx] = pm;
      *(uint2*)&Ng[mb + (4 * ty + r) * 64 + 4 * tx] = pn;
    }
  }
}

__global__ __launch_bounds__(256, 1) void delta_p2(const u16* __restrict__ Mg,
                                                   const u16* __restrict__ Ng,
                                                   float* __restrict__ Wg)
{
  __shared__ float Ws[64][CPAD];
  __shared__ float Ms[64][CPAD];
  __shared__ float Ns[64][CPAD];
  const int bh = blockIdx.x;
  const int tid = threadIdx.x;
  const int tx = tid & 15, ty = tid >> 4;
  for (int i = tid; i < 64 * CPAD; i += 256) (&Ws[0][0])[i] = 0.f;
  __syncthreads();

  for (int j = 0; j < NCH_; ++j) {
    size_t base = ((size_t)bh * NCH_ + j) * 4096;
    const uint2* M2 = (const uint2*)(Mg + base);
    const uint2* N2 = (const uint2*)(Ng + base);
    float4* W4 = (float4*)(Wg + base);
    #pragma unroll
    for (int i = 0; i < 4; ++i) {
      int idx4 = i * 256 + tid;               // 0..1023, 4 elems each
      int row = idx4 >> 4, c0 = (idx4 & 15) * 4;
      uint2 m2 = M2[idx4];
      Ms[row][c0]     = bf2f((u16)(m2.x & 0xffff));
      Ms[row][c0 + 1] = bf2f((u16)(m2.x >> 16));
      Ms[row][c0 + 2] = bf2f((u16)(m2.y & 0xffff));
      Ms[row][c0 + 3] = bf2f((u16)(m2.y >> 16));
      uint2 n2 = N2[idx4];
      Ns[row][c0]     = bf2f((u16)(n2.x & 0xffff));
      Ns[row][c0 + 1] = bf2f((u16)(n2.x >> 16));
      Ns[row][c0 + 2] = bf2f((u16)(n2.y & 0xffff));
      Ns[row][c0 + 3] = bf2f((u16)(n2.y >> 16));
      W4[idx4] = make_float4(Ws[row][c0], Ws[row][c0 + 1], Ws[row][c0 + 2], Ws[row][c0 + 3]);
    }
    __syncthreads();
    float acc[4][4] = {};
    #pragma unroll 8
    for (int e = 0; e < 64; ++e) {
      float xr[4], yc[4];
      #pragma unroll
      for (int r = 0; r < 4; ++r) xr[r] = Ws[4 * ty + r][e];
      #pragma unroll
      for (int c = 0; c < 4; ++c) yc[c] = Ms[e][4 * tx + c];
      #pragma unroll
      for (int r = 0; r < 4; ++r)
        #pragma unroll
        for (int c = 0; c < 4; ++c) acc[r][c] = fmaf(xr[r], yc[c], acc[r][c]);
    }
    __syncthreads();
    #pragma unroll
    for (int r = 0; r < 4; ++r)
      #pragma unroll
      for (int c = 0; c < 4; ++c)
        Ws[4 * ty + r][4 * tx + c] += Ns[4 * ty + r][4 * tx + c] - acc[r][c];
    __syncthreads();
  }
}

__global__ __launch_bounds__(256, 1) void delta_p3(const float* __restrict__ qkvb,
                                                   const float* __restrict__ Wg,
                                                   float* __restrict__ attn)
{
  __shared__ float Kc[64][CPAD];
  __shared__ float Qc[64][CPAD];
  __shared__ float Wb[64][CPAD];   // W_j, later reused for G
  __shared__ float Am[64][CPAD];
  __shared__ float Um[64][CPAD];
  __shared__ float bet[64];
  const int id5 = blockIdx.x;
  const int bh = id5 >> 5;
  const int b = bh & 7, h = bh >> 3;
  const int t0 = (id5 & 31) * 64;
  const int tid = threadIdx.x;
  const int tx = tid & 15, ty = tid >> 4;
  const int wid = tid >> 6, lane = tid & 63;
  const size_t hoff = (size_t)h * 193;

  #pragma unroll
  for (int i = 0; i < 16; ++i) {
    int idx = i * 256 + tid, row = idx >> 6, col = idx & 63;
    size_t gb = ((size_t)(t0 + row) * B_ + b) * QKVB_ + hoff;
    Qc[row][col] = qkvb[gb + col];
    Kc[row][col] = qkvb[gb + 64 + col];
  }
  {
    const float4* W4 = (const float4*)(Wg + (size_t)id5 * 4096);
    #pragma unroll
    for (int i = 0; i < 4; ++i) {
      int idx4 = i * 256 + tid;
      int row = idx4 >> 4, c0 = (idx4 & 15) * 4;
      float4 w4 = W4[idx4];
      Wb[row][c0] = w4.x; Wb[row][c0 + 1] = w4.y; Wb[row][c0 + 2] = w4.z; Wb[row][c0 + 3] = w4.w;
    }
  }
  if (tid < 64) bet[tid] = qkvb[((size_t)(t0 + tid) * B_ + b) * QKVB_ + hoff + 192];
  __syncthreads();

  float kw[4][4] = {}, qw[4][4] = {};
  #pragma unroll 4
  for (int e = 0; e < 64; ++e) {
    float k4[4], q4[4], w4[4];
    #pragma unroll
    for (int r = 0; r < 4; ++r) { k4[r] = Kc[4 * ty + r][e]; q4[r] = Qc[4 * ty + r][e]; }
    #pragma unroll
    for (int c = 0; c < 4; ++c) w4[c] = Wb[4 * tx + c][e];
    #pragma unroll
    for (int r = 0; r < 4; ++r)
      #pragma unroll
      for (int c = 0; c < 4; ++c) {
        kw[r][c] = fmaf(k4[r], w4[c], kw[r][c]);
        qw[r][c] = fmaf(q4[r], w4[c], qw[r][c]);
      }
  }
  {
    float acc[4][4] = {};
    #pragma unroll 8
    for (int e = 0; e < 64; ++e) {
      float xr[4], yc[4];
      #pragma unroll
      for (int r = 0; r < 4; ++r) xr[r] = Kc[4 * ty + r][e];
      #pragma unroll
      for (int c = 0; c < 4; ++c) yc[c] = Kc[4 * tx + c][e];
      #pragma unroll
      for (int r = 0; r < 4; ++r)
        #pragma unroll
        for (int c = 0; c < 4; ++c) acc[r][c] = fmaf(xr[r], yc[c], acc[r][c]);
    }
    #pragma unroll
    for (int r = 0; r < 4; ++r) {
      float bt_ = bet[4 * ty + r];
      #pragma unroll
      for (int c = 0; c < 4; ++c) Am[4 * ty + r][4 * tx + c] = bt_ * acc[r][c];
    }
  }
  #pragma unroll
  for (int r = 0; r < 4; ++r) {
    size_t gb = ((size_t)(t0 + 4 * ty + r) * B_ + b) * QKVB_ + hoff + 128;
    float bt_ = bet[4 * ty + r];
    #pragma unroll
    for (int c = 0; c < 4; ++c) {
      float v = qkvb[gb + 4 * tx + c];
      Um[4 * ty + r][4 * tx + c] = bt_ * (v - kw[r][c]);
    }
  }
  __syncthreads();

  #pragma unroll 1
  for (int blk = 0; blk < 4; ++blk) {
    if (wid == blk) {
      const int r0 = blk * 16;
      float u[16];
      #pragma unroll
      for (int i = 0; i < 16; ++i) u[i] = Um[r0 + i][lane];
      #pragma unroll
      for (int jj = 0; jj < 15; ++jj) {
        float uj = u[jj];
        #pragma unroll
        for (int t = jj + 1; t < 16; ++t)
          u[t] = fmaf(-Am[r0 + t][r0 + jj], uj, u[t]);
      }
      #pragma unroll
      for (int i = 0; i < 16; ++i) Um[r0 + i][lane] = u[i];
    }
    __syncthreads();
    if (wid > blk) {
      const int r0 = blk * 16, rw = wid * 16;
      float u[16];
      #pragma unroll
      for (int i = 0; i < 16; ++i) u[i] = Um[rw + i][lane];
      #pragma unroll
      for (int jj = 0; jj < 16; ++jj) {
        float uj = Um[r0 + jj][lane];
        #pragma unroll
        for (int i = 0; i < 16; ++i)
          u[i] = fmaf(-Am[rw + i][r0 + jj], uj, u[i]);
      }
      #pragma unroll
      for (int i = 0; i < 16; ++i) Um[rw + i][lane] = u[i];
    }
    __syncthreads();
  }

  // G = tril(Q K^T) into Wb (W dead)
  {
    float acc[4][4] = {};
    #pragma unroll 8
    for (int e = 0; e < 64; ++e) {
      float xr[4], yc[4];
      #pragma unroll
      for (int r = 0; r < 4; ++r) xr[r] = Qc[4 * ty + r][e];
      #pragma unroll
      for (int c = 0; c < 4; ++c) yc[c] = Kc[4 * tx + c][e];
      #pragma unroll
      for (int r = 0; r < 4; ++r)
        #pragma unroll
        for (int c = 0; c < 4; ++c) acc[r][c] = fmaf(xr[r], yc[c], acc[r][c]);
    }
    #pragma unroll
    for (int r = 0; r < 4; ++r)
      #pragma unroll
      for (int c = 0; c < 4; ++c)
        Wb[4 * ty + r][4 * tx + c] = (4 * tx + c <= 4 * ty + r) ? acc[r][c] : 0.f;
  }
  __syncthreads();

  // Out = qw + G U
  {
    float acc[4][4];
    #pragma unroll
    for (int r = 0; r < 4; ++r)
      #pragma unroll
      for (int c = 0; c < 4; ++c) acc[r][c] = qw[r][c];
    #pragma unroll 8
    for (int t = 0; t < 64; ++t) {
      float xr[4], yc[4];
      #pragma unroll
      for (int r = 0; r < 4; ++r) xr[r] = Wb[4 * ty + r][t];
      #pragma unroll
      for (int c = 0; c < 4; ++c) yc[c] = Um[t][4 * tx + c];
      #pragma unroll
      for (int r = 0; r < 4; ++r)
        #pragma unroll
        for (int c = 0; c < 4; ++c) acc[r][c] = fmaf(xr[r], yc[c], acc[r][c]);
    }
    #pragma unroll
    for (int r = 0; r < 4; ++r)
      *(float4*)&attn[((size_t)(t0 + 4 * ty + r) * B_ + b) * HID_ + h * 64 + 4 * tx] =
          make_float4(acc[r][0], acc[r][1], acc[r][2], acc[r][3]);
  }
}

// ---------------------------------------------------------------------------
__global__ __launch_bounds__(128) void transpose_sb_to_bs(const float* __restrict__ in,
                                                          float* __restrict__ out)
{
  size_t m = blockIdx.x;
  size_t s = m >> 3, b = m & 7;
  const float4* src = (const float4*)(in + m * HID_);
  float4* dst = (float4*)(out + (b * (size_t)S_ + s) * HID_);
  dst[threadIdx.x] = src[threadIdx.x];
}

// ---------------------------------------------------------------------------
extern "C" void kernel_launch(void* const* d_in, const int* in_sizes, int n_in,
                              void* d_out, int out_size, void* d_ws, size_t ws_size,
                              hipStream_t stream)
{
  const float* x        = (const float*)d_in[0];
  const float* ip_w     = (const float*)d_in[1];
  const float* ip_b     = (const float*)d_in[2];
  const float* fw_ln_g  = (const float*)d_in[3];
  const float* fw_ln_b  = (const float*)d_in[4];
  const float* fw_slow_w = (const float*)d_in[5];
  const float* fw_out_w  = (const float*)d_in[6];
  const float* ff_ln_g  = (const float*)d_in[7];
  const float* ff_ln_b  = (const float*)d_in[8];
  const float* ff_w1    = (const float*)d_in[9];
  const float* ff_b1    = (const float*)d_in[10];
  const float* ff_w2    = (const float*)d_in[11];
  const float* ff_b2    = (const float*)d_in[12];
  float* out = (float*)d_out;

  const int M = B_ * S_;  // 16384
  const size_t matN = (size_t)64 * NCH_ * 4096;  // 8.39M elems per 64x64xchunks matrix

  size_t need = ((size_t)M * (HID_ + QKVB_ + HID_)) * sizeof(float);
  if (ws_size < need) return;

  float* cur  = (float*)d_ws;
  float* qkvb = cur + (size_t)M * HID_;
  float* attn = qkvb + (size_t)M * QKVB_;
  // delta scratch aliases: M,N (bf16) fill the attn slot exactly; W (fp32) = d_out
  u16*   Mg   = (u16*)attn;
  u16*   Ng   = Mg + matN;
  float* Wg   = out;
  float* big  = qkvb;     // FFN hidden aliases qkvb+attn region (M*2056 >= M*2048)
  float* tmp  = out;      // LN scratch; dead whenever Wg is live and vice versa

  dim3 blk(256);

  gemm_mfma<true, false, false, true><<<dim3(HID_ / 128, M / 128), blk, 0, stream>>>(
      x, ip_w, ip_b, nullptr, cur, M, HID_, HID_);

  for (int layer = 0; layer < 2; ++layer) {
    const float* sw = fw_slow_w + (size_t)layer * QKVB_ * HID_;
    const float* ow = fw_out_w  + (size_t)layer * HID_ * HID_;

    ln_k<<<M, 64, 0, stream>>>(cur, fw_ln_g + layer * HID_, fw_ln_b + layer * HID_, tmp);
    gemm_mfma<false, false, false, false><<<dim3((QKVB_ + 127) / 128, M / 128), blk, 0, stream>>>(
        tmp, sw, nullptr, nullptr, qkvb, M, QKVB_, HID_);
    qkvb_transform<<<(size_t)M * H_, 64, 0, stream>>>(qkvb);
    delta_p1<<<64 * NCH_, 256, 0, stream>>>(qkvb, Mg, Ng);
    delta_p2<<<64, 256, 0, stream>>>(Mg, Ng, Wg);
    delta_p3<<<64 * NCH_, 256, 0, stream>>>(qkvb, Wg, attn);
    gemm_mfma<false, false, true, false><<<dim3(HID_ / 128, M / 128), blk, 0, stream>>>(
        attn, ow, nullptr, cur, cur, M, HID_, HID_);

    if (layer == 0) {
      ln_k<<<M, 64, 0, stream>>>(cur, ff_ln_g, ff_ln_b, tmp);
      gemm_mfma<true, true, false, false><<<dim3(FF_ / 128, M / 128), blk, 0, stream>>>(
          tmp, ff_w1, ff_b1, nullptr, big, M, FF_, HID_);
      gemm_mfma<true, false, true, false><<<dim3(HID_ / 128, M / 128), blk, 0, stream>>>(
          big, ff_w2, ff_b2, cur, cur, M, HID_, FF_);
    }
  }

  transpose_sb_to_bs<<<M, 128, 0, stream>>>(cur, out);
}

// Round 5
// 882.849 us; speedup vs baseline: 7.6602x; 1.6410x over previous
//
#include <hip/hip_runtime.h>
#include <hip/hip_bf16.h>

#define B_    8
#define S_    2048
#define HID_  512
#define H_    8
#define D_    64
#define FF_   2048
#define QKVB_ 1544   // H*(3*D+1) = 8*193
#define NCH_  32     // S/64 chunks

typedef unsigned short u16;
typedef __attribute__((ext_vector_type(8))) short short8;
typedef __attribute__((ext_vector_type(4))) float f32x4;

__device__ __forceinline__ u16 f2bf(float x) {           // RNE fp32->bf16
  unsigned u = __builtin_bit_cast(unsigned, x);
  unsigned r = (u + 0x7FFFu + ((u >> 16) & 1u)) >> 16;
  return (u16)r;
}
__device__ __forceinline__ float bf2f(u16 v) {
  return __builtin_bit_cast(float, (unsigned)v << 16);
}

// 64x64x64 product C[r][c] = sum_k F[r][k]*G[c][k], operands bf16 in LDS with
// row strides FS/GS (u16 units; must be mult of 8 for 16B-aligned b128 reads).
// Wave computes rows wrow0..wrow0+15, all 64 cols (4 tiles, K=64 = 2 MFMA).
template<int FS, int GS>
__device__ __forceinline__ void prod64(const u16* __restrict__ F,
                                       const u16* __restrict__ G,
                                       int wrow0, int lane, f32x4 acc[4])
{
  short8 f0 = *(const short8*)&F[(wrow0 + (lane & 15)) * FS + ((lane >> 4) * 8)];
  short8 f1 = *(const short8*)&F[(wrow0 + (lane & 15)) * FS + 32 + ((lane >> 4) * 8)];
  #pragma unroll
  for (int c0 = 0; c0 < 4; ++c0) {
    short8 g0 = *(const short8*)&G[(c0 * 16 + (lane & 15)) * GS + ((lane >> 4) * 8)];
    short8 g1 = *(const short8*)&G[(c0 * 16 + (lane & 15)) * GS + 32 + ((lane >> 4) * 8)];
    acc[c0] = __builtin_amdgcn_mfma_f32_16x16x32_bf16(f0, g0, acc[c0], 0, 0, 0);
    acc[c0] = __builtin_amdgcn_mfma_f32_16x16x32_bf16(f1, g1, acc[c0], 0, 0, 0);
  }
}

// ---------------------------------------------------------------------------
// bf16 MFMA GEMM (unchanged from round 4)
// ---------------------------------------------------------------------------
template<bool BIAS, bool RELU, bool RES, bool ASWAP>
__global__ __launch_bounds__(256) void gemm_mfma(
    const float* __restrict__ A, const float* __restrict__ Wt,
    const float* __restrict__ bias, const float* __restrict__ res,
    float* __restrict__ C, int M, int N, int K)
{
  __shared__ u16 As[128 * 40];
  __shared__ u16 Bs[128 * 40];
  const int tid = threadIdx.x;
  const int bm = blockIdx.y * 128, bn = blockIdx.x * 128;
  const int wave = tid >> 6, lane = tid & 63;
  const int wr = wave >> 1, wc = wave & 1;
  const int row16 = lane & 15, kg = lane >> 4;
  const int srow = tid >> 1, sh = tid & 1;

  f32x4 acc[4][4] = {};

  const int ktiles = K >> 5;
  for (int kt = 0; kt < ktiles; ++kt) {
    const int k0 = kt << 5;
    float4 av[4], wv[4];
    {
      int am = bm + srow;
      int garow = ASWAP ? ((am & 7) * S_ + (am >> 3)) : am;
      const float4* ap = (const float4*)(A + (size_t)garow * K + k0 + sh * 16);
      av[0] = ap[0]; av[1] = ap[1]; av[2] = ap[2]; av[3] = ap[3];
      int wn = bn + srow;
      if (wn < N) {
        const float4* wp = (const float4*)(Wt + (size_t)wn * K + k0 + sh * 16);
        wv[0] = wp[0]; wv[1] = wp[1]; wv[2] = wp[2]; wv[3] = wp[3];
      } else {
        wv[0] = wv[1] = wv[2] = wv[3] = make_float4(0.f, 0.f, 0.f, 0.f);
      }
    }
    __syncthreads();
    {
      union { u16 u[16]; short8 s[2]; } pa, pw;
      #pragma unroll
      for (int v = 0; v < 4; ++v) {
        const float4 a4 = av[v], w4 = wv[v];
        pa.u[v * 4 + 0] = f2bf(a4.x); pa.u[v * 4 + 1] = f2bf(a4.y);
        pa.u[v * 4 + 2] = f2bf(a4.z); pa.u[v * 4 + 3] = f2bf(a4.w);
        pw.u[v * 4 + 0] = f2bf(w4.x); pw.u[v * 4 + 1] = f2bf(w4.y);
        pw.u[v * 4 + 2] = f2bf(w4.z); pw.u[v * 4 + 3] = f2bf(w4.w);
      }
      *(short8*)&As[srow * 40 + sh * 16]     = pa.s[0];
      *(short8*)&As[srow * 40 + sh * 16 + 8] = pa.s[1];
      *(short8*)&Bs[srow * 40 + sh * 16]     = pw.s[0];
      *(short8*)&Bs[srow * 40 + sh * 16 + 8] = pw.s[1];
    }
    __syncthreads();
    short8 af[4], bfr[4];
    #pragma unroll
    for (int m = 0; m < 4; ++m)
      af[m] = *(const short8*)&As[(wr * 64 + m * 16 + row16) * 40 + kg * 8];
    #pragma unroll
    for (int n = 0; n < 4; ++n)
      bfr[n] = *(const short8*)&Bs[(wc * 64 + n * 16 + row16) * 40 + kg * 8];
    #pragma unroll
    for (int m = 0; m < 4; ++m)
      #pragma unroll
      for (int n = 0; n < 4; ++n)
        acc[m][n] = __builtin_amdgcn_mfma_f32_16x16x32_bf16(af[m], bfr[n], acc[m][n], 0, 0, 0);
  }

  #pragma unroll
  for (int m = 0; m < 4; ++m) {
    #pragma unroll
    for (int n = 0; n < 4; ++n) {
      const int gcol = bn + wc * 64 + n * 16 + row16;
      if (gcol < N) {
        #pragma unroll
        for (int j = 0; j < 4; ++j) {
          const int grow = bm + wr * 64 + m * 16 + kg * 4 + j;
          float v = acc[m][n][j];
          if (BIAS) v += bias[gcol];
          if (RES)  v += res[(size_t)grow * N + gcol];
          if (RELU) v = fmaxf(v, 0.f);
          C[(size_t)grow * N + gcol] = v;
        }
      }
    }
  }
}

// ---------------------------------------------------------------------------
__global__ __launch_bounds__(64) void ln_k(const float* __restrict__ x,
    const float* __restrict__ g, const float* __restrict__ bt,
    float* __restrict__ o)
{
  size_t row = blockIdx.x;
  int lane = threadIdx.x;
  const float4* xr = (const float4*)(x + row * HID_);
  float4 v0 = xr[lane];
  float4 v1 = xr[64 + lane];
  float s  = v0.x + v0.y + v0.z + v0.w + v1.x + v1.y + v1.z + v1.w;
  float ss = v0.x*v0.x + v0.y*v0.y + v0.z*v0.z + v0.w*v0.w
           + v1.x*v1.x + v1.y*v1.y + v1.z*v1.z + v1.w*v1.w;
  #pragma unroll
  for (int off = 32; off; off >>= 1) {
    s  += __shfl_xor(s, off);
    ss += __shfl_xor(ss, off);
  }
  float mean = s * (1.f / HID_);
  float inv  = rsqrtf(ss * (1.f / HID_) - mean * mean + 1e-5f);
  const float4* gv = (const float4*)g;
  const float4* bv = (const float4*)bt;
  float4 g0 = gv[lane], g1 = gv[64 + lane];
  float4 b0 = bv[lane], b1 = bv[64 + lane];
  float4 r0, r1;
  r0.x = (v0.x - mean) * inv * g0.x + b0.x;
  r0.y = (v0.y - mean) * inv * g0.y + b0.y;
  r0.z = (v0.z - mean) * inv * g0.z + b0.z;
  r0.w = (v0.w - mean) * inv * g0.w + b0.w;
  r1.x = (v1.x - mean) * inv * g1.x + b1.x;
  r1.y = (v1.y - mean) * inv * g1.y + b1.y;
  r1.z = (v1.z - mean) * inv * g1.z + b1.z;
  r1.w = (v1.w - mean) * inv * g1.w + b1.w;
  float4* ov = (float4*)(o + row * HID_);
  ov[lane] = r0;
  ov[64 + lane] = r1;
}

// ---------------------------------------------------------------------------
__global__ __launch_bounds__(64) void qkvb_transform(float* __restrict__ qkvb)
{
  size_t r = blockIdx.x;
  float* base = qkvb + (r >> 3) * (size_t)QKVB_ + (r & 7) * 193;
  int lane = threadIdx.x;
  float q = base[lane], k = base[64 + lane];
  float mq = q, mk = k;
  #pragma unroll
  for (int off = 32; off; off >>= 1) {
    mq = fmaxf(mq, __shfl_xor(mq, off));
    mk = fmaxf(mk, __shfl_xor(mk, off));
  }
  float eq = __expf(q - mq), ek = __expf(k - mk);
  float sq = eq, sk = ek;
  #pragma unroll
  for (int off = 32; off; off >>= 1) { sq += __shfl_xor(sq, off); sk += __shfl_xor(sk, off); }
  base[lane]      = eq / sq;
  base[64 + lane] = ek / sk;
  if (lane == 0) { float bb = base[192]; base[192] = 1.f / (1.f + __expf(-bb)); }
}

// ---------------------------------------------------------------------------
// Delta rule, 3-phase chunked WY form, MFMA edition.
//   p1: A = beta⊙KK^T (MFMA); solve (I+A){U0,CK}={bV,bK} (fp32 VALU);
//       store CK,U0^T bf16; MT = K^T·CK, N = U0^T·K (MFMA) -> bf16.
//   p2: W_{j+1} = W_j(I−M)+N (MFMA, serial); snapshots W_j fp32 -> qkvb V-region.
//   p3: U = U0 − CK·W0^T; Out = Q·W0^T + tril(QK^T)·U  (all MFMA, no solve).
// ---------------------------------------------------------------------------
__global__ __launch_bounds__(256, 2) void delta_p1(const float* __restrict__ qkvb,
                                                   u16* __restrict__ MTg,
                                                   u16* __restrict__ Ng,
                                                   u16* __restrict__ CKg,
                                                   u16* __restrict__ U0Tg)
{
  __shared__ __align__(16) u16 Kb[64 * 72];
  __shared__ __align__(16) float Am[64][65];
  __shared__ __align__(16) float Uv[64][65];
  __shared__ __align__(16) float Uk[64][65];
  __shared__ __align__(16) u16 CKTb[64 * 72];
  __shared__ __align__(16) u16 U0Tb[64 * 72];
  __shared__ float bet[64];
  u16* KTb = (u16*)&Am[0][0];   // stride 88: 64*88*2 = 11264B <= 16640B

  const int id5 = blockIdx.x, bh = id5 >> 5;
  const int b = bh & 7, h = bh >> 3, t0 = (id5 & 31) * 64;
  const int tid = threadIdx.x, lane = tid & 63, wv = tid >> 6;
  const int wid = wv, wrow0 = wv * 16;
  const size_t hoff = (size_t)h * 193;

  #pragma unroll
  for (int i = 0; i < 16; ++i) {
    int idx = i * 256 + tid, row = idx >> 6, col = idx & 63;
    size_t gb = ((size_t)(t0 + row) * B_ + b) * QKVB_ + hoff;
    Kb[row * 72 + col] = f2bf(qkvb[gb + 64 + col]);
  }
  if (tid < 64) bet[tid] = qkvb[((size_t)(t0 + tid) * B_ + b) * QKVB_ + hoff + 192];
  __syncthreads();

  // A = beta ⊙ K K^T (MFMA) ; Uv = beta*V ; Uk = beta*K (fp32)
  {
    f32x4 a[4] = {};
    prod64<72, 72>(Kb, Kb, wrow0, lane, a);
    #pragma unroll
    for (int c0 = 0; c0 < 4; ++c0)
      #pragma unroll
      for (int j = 0; j < 4; ++j) {
        int row = wrow0 + (lane >> 4) * 4 + j, col = c0 * 16 + (lane & 15);
        Am[row][col] = bet[row] * a[c0][j];
      }
  }
  #pragma unroll
  for (int i = 0; i < 16; ++i) {
    int idx = i * 256 + tid, row = idx >> 6, col = idx & 63;
    size_t gb = ((size_t)(t0 + row) * B_ + b) * QKVB_ + hoff;
    float bt_ = bet[row];
    Uv[row][col] = bt_ * qkvb[gb + 128 + col];
    Uk[row][col] = bt_ * bf2f(Kb[row * 72 + col]);
  }
  __syncthreads();

  // two-RHS blocked forward substitution: (I+A){U0,CK} = {bV,bK}
  #pragma unroll 1
  for (int blk = 0; blk < 4; ++blk) {
    if (wid == blk) {
      const int r0 = blk * 16;
      float uv[16], uk[16];
      #pragma unroll
      for (int i = 0; i < 16; ++i) { uv[i] = Uv[r0 + i][lane]; uk[i] = Uk[r0 + i][lane]; }
      #pragma unroll
      for (int jj = 0; jj < 15; ++jj) {
        #pragma unroll
        for (int t = jj + 1; t < 16; ++t) {
          float a = Am[r0 + t][r0 + jj];
          uv[t] = fmaf(-a, uv[jj], uv[t]);
          uk[t] = fmaf(-a, uk[jj], uk[t]);
        }
      }
      #pragma unroll
      for (int i = 0; i < 16; ++i) { Uv[r0 + i][lane] = uv[i]; Uk[r0 + i][lane] = uk[i]; }
    }
    __syncthreads();
    if (wid > blk) {
      const int r0 = blk * 16, rw = wid * 16;
      float uv[16], uk[16];
      #pragma unroll
      for (int i = 0; i < 16; ++i) { uv[i] = Uv[rw + i][lane]; uk[i] = Uk[rw + i][lane]; }
      #pragma unroll
      for (int jj = 0; jj < 16; ++jj) {
        float sv = Uv[r0 + jj][lane], sk = Uk[r0 + jj][lane];
        #pragma unroll
        for (int i = 0; i < 16; ++i) {
          float a = Am[rw + i][r0 + jj];
          uv[i] = fmaf(-a, sv, uv[i]);
          uk[i] = fmaf(-a, sk, uk[i]);
        }
      }
      #pragma unroll
      for (int i = 0; i < 16; ++i) { Uv[rw + i][lane] = uv[i]; Uk[rw + i][lane] = uk[i]; }
    }
    __syncthreads();
  }

  // post-solve: global CK (row-major) + U0T, LDS CKTb/U0Tb/KTb
  const int prow = tid >> 2, pc0 = (tid & 3) * 16;
  const size_t mb = (size_t)id5 * 4096;
  {
    union { u16 u[16]; uint4 v[2]; } pk, pu;
    #pragma unroll
    for (int i = 0; i < 16; ++i) pk.u[i] = f2bf(Uk[prow][pc0 + i]);     // CK[t][d]
    #pragma unroll
    for (int i = 0; i < 16; ++i) pu.u[i] = f2bf(Uv[pc0 + i][prow]);     // U0T[d][t]
    *(uint4*)&CKg[mb + prow * 64 + pc0]      = pk.v[0];
    *(uint4*)&CKg[mb + prow * 64 + pc0 + 8]  = pk.v[1];
    *(uint4*)&U0Tg[mb + prow * 64 + pc0]     = pu.v[0];
    *(uint4*)&U0Tg[mb + prow * 64 + pc0 + 8] = pu.v[1];
    *(short8*)&U0Tb[prow * 72 + pc0]     = *(short8*)&pu.u[0];
    *(short8*)&U0Tb[prow * 72 + pc0 + 8] = *(short8*)&pu.u[8];
    #pragma unroll
    for (int i = 0; i < 16; ++i) CKTb[prow * 72 + pc0 + i] = f2bf(Uk[pc0 + i][prow]);
    #pragma unroll
    for (int i = 0; i < 16; ++i) KTb[prow * 88 + pc0 + i] = Kb[(pc0 + i) * 72 + prow];
  }
  __syncthreads();

  // MT[e][f] = sum_t K[t][e]CK[t][f] ; N[d][e] = sum_t U0[t][d]K[t][e]
  {
    f32x4 am[4] = {}, an[4] = {};
    prod64<88, 72>(KTb, CKTb, wrow0, lane, am);
    prod64<72, 88>(U0Tb, KTb, wrow0, lane, an);
    u16* MTs = (u16*)&Uv[0][0];   // stride-64 staging (Uv/Uk dead)
    u16* Ns  = (u16*)&Uk[0][0];
    #pragma unroll
    for (int c0 = 0; c0 < 4; ++c0)
      #pragma unroll
      for (int j = 0; j < 4; ++j) {
        int row = wrow0 + (lane >> 4) * 4 + j, col = c0 * 16 + (lane & 15);
        MTs[row * 64 + col] = f2bf(am[c0][j]);
        Ns[row * 64 + col]  = f2bf(an[c0][j]);
      }
  }
  __syncthreads();
  {
    const u16* MTs = (const u16*)&Uv[0][0];
    const u16* Ns  = (const u16*)&Uk[0][0];
    *(uint4*)&MTg[mb + prow * 64 + pc0]     = ((const uint4*)&MTs[prow * 64 + pc0])[0];
    *(uint4*)&MTg[mb + prow * 64 + pc0 + 8] = ((const uint4*)&MTs[prow * 64 + pc0])[1];
    *(uint4*)&Ng[mb + prow * 64 + pc0]      = ((const uint4*)&Ns[prow * 64 + pc0])[0];
    *(uint4*)&Ng[mb + prow * 64 + pc0 + 8]  = ((const uint4*)&Ns[prow * 64 + pc0])[1];
  }
}

__global__ __launch_bounds__(256, 1) void delta_p2(const u16* __restrict__ MTg,
                                                   const u16* __restrict__ Ng,
                                                   float* __restrict__ qkvb)
{
  __shared__ float Ws[64][65];
  __shared__ __align__(16) u16 Wbf[64 * 72];
  __shared__ __align__(16) u16 MTb[64 * 72];
  __shared__ __align__(16) u16 Nb[64 * 72];
  const int bh = blockIdx.x, b = bh & 7, h = bh >> 3;
  const int tid = threadIdx.x, lane = tid & 63, wv = tid >> 6, wrow0 = wv * 16;
  const size_t hoff = (size_t)h * 193;
  const int prow = tid >> 2, pc0 = (tid & 3) * 16;

  for (int i = tid; i < 64 * 65; i += 256) (&Ws[0][0])[i] = 0.f;
  for (int i = tid; i < 64 * 72; i += 256) Wbf[i] = 0;
  __syncthreads();

  for (int j = 0; j < NCH_; ++j) {
    size_t base = ((size_t)bh * NCH_ + j) * 4096;
    {
      uint4 m0 = *(const uint4*)&MTg[base + prow * 64 + pc0];
      uint4 m1 = *(const uint4*)&MTg[base + prow * 64 + pc0 + 8];
      uint4 n0 = *(const uint4*)&Ng[base + prow * 64 + pc0];
      uint4 n1 = *(const uint4*)&Ng[base + prow * 64 + pc0 + 8];
      *(short8*)&MTb[prow * 72 + pc0]     = __builtin_bit_cast(short8, m0);
      *(short8*)&MTb[prow * 72 + pc0 + 8] = __builtin_bit_cast(short8, m1);
      *(short8*)&Nb[prow * 72 + pc0]      = __builtin_bit_cast(short8, n0);
      *(short8*)&Nb[prow * 72 + pc0 + 8]  = __builtin_bit_cast(short8, n1);
    }
    // W0 snapshot (pre-update) -> qkvb V region, fp32
    {
      const int t0 = j * 64;
      #pragma unroll
      for (int i = 0; i < 16; ++i)
        qkvb[((size_t)(t0 + prow) * B_ + b) * QKVB_ + hoff + 128 + pc0 + i] = Ws[prow][pc0 + i];
    }
    __syncthreads();
    f32x4 a[4] = {};
    prod64<72, 72>(Wbf, MTb, wrow0, lane, a);   // (W·M)[d][e]
    #pragma unroll
    for (int c0 = 0; c0 < 4; ++c0)
      #pragma unroll
      for (int jj = 0; jj < 4; ++jj) {
        int row = wrow0 + (lane >> 4) * 4 + jj, col = c0 * 16 + (lane & 15);
        float w = Ws[row][col] + bf2f(Nb[row * 72 + col]) - a[c0][jj];
        Ws[row][col] = w;
        Wbf[row * 72 + col] = f2bf(w);
      }
    __syncthreads();
  }
}

__global__ __launch_bounds__(256, 2) void delta_p3(const float* __restrict__ qkvb,
                                                   const u16* __restrict__ CKg,
                                                   const u16* __restrict__ U0Tg,
                                                   float* __restrict__ attn)
{
  __shared__ __align__(16) u16 Qb[64 * 72];
  __shared__ __align__(16) u16 Kb[64 * 72];
  __shared__ __align__(16) u16 W0b[64 * 72];
  __shared__ __align__(16) u16 CKb[64 * 72];
  __shared__ __align__(16) u16 U0Tb[64 * 72];
  __shared__ __align__(16) u16 Gb[64 * 72];
  __shared__ __align__(16) u16 UTb[64 * 72];

  const int id5 = blockIdx.x, bh = id5 >> 5;
  const int b = bh & 7, h = bh >> 3, t0 = (id5 & 31) * 64;
  const int tid = threadIdx.x, lane = tid & 63, wv = tid >> 6, wrow0 = wv * 16;
  const size_t hoff = (size_t)h * 193;
  const int prow = tid >> 2, pc0 = (tid & 3) * 16;
  const size_t mb = (size_t)id5 * 4096;

  #pragma unroll
  for (int i = 0; i < 16; ++i) {
    int idx = i * 256 + tid, row = idx >> 6, col = idx & 63;
    size_t gb = ((size_t)(t0 + row) * B_ + b) * QKVB_ + hoff;
    Qb[row * 72 + col]  = f2bf(qkvb[gb + col]);
    Kb[row * 72 + col]  = f2bf(qkvb[gb + 64 + col]);
    W0b[row * 72 + col] = f2bf(qkvb[gb + 128 + col]);   // W0[d][e] from V region
  }
  {
    uint4 c0v = *(const uint4*)&CKg[mb + prow * 64 + pc0];
    uint4 c1v = *(const uint4*)&CKg[mb + prow * 64 + pc0 + 8];
    uint4 u0v = *(const uint4*)&U0Tg[mb + prow * 64 + pc0];
    uint4 u1v = *(const uint4*)&U0Tg[mb + prow * 64 + pc0 + 8];
    *(short8*)&CKb[prow * 72 + pc0]      = __builtin_bit_cast(short8, c0v);
    *(short8*)&CKb[prow * 72 + pc0 + 8]  = __builtin_bit_cast(short8, c1v);
    *(short8*)&U0Tb[prow * 72 + pc0]     = __builtin_bit_cast(short8, u0v);
    *(short8*)&U0Tb[prow * 72 + pc0 + 8] = __builtin_bit_cast(short8, u1v);
  }
  __syncthreads();

  f32x4 ag[4] = {}, ac[4] = {}, ab[4] = {};
  prod64<72, 72>(Qb, Kb, wrow0, lane, ag);    // QK^T
  prod64<72, 72>(W0b, CKb, wrow0, lane, ac);  // (W0·CK^T)[d][t]
  prod64<72, 72>(Qb, W0b, wrow0, lane, ab);   // Q·W0^T

  #pragma unroll
  for (int c0 = 0; c0 < 4; ++c0)
    #pragma unroll
    for (int j = 0; j < 4; ++j) {
      int row = wrow0 + (lane >> 4) * 4 + j, col = c0 * 16 + (lane & 15);
      Gb[row * 72 + col]  = f2bf(col <= row ? ag[c0][j] : 0.f);
      UTb[row * 72 + col] = f2bf(bf2f(U0Tb[row * 72 + col]) - ac[c0][j]);
    }
  __syncthreads();

  prod64<72, 72>(Gb, UTb, wrow0, lane, ab);   // += G·U

  #pragma unroll
  for (int c0 = 0; c0 < 4; ++c0)
    #pragma unroll
    for (int j = 0; j < 4; ++j) {
      int row = wrow0 + (lane >> 4) * 4 + j, col = c0 * 16 + (lane & 15);
      attn[((size_t)(t0 + row) * B_ + b) * HID_ + h * 64 + col] = ab[c0][j];
    }
}

// ---------------------------------------------------------------------------
__global__ __launch_bounds__(128) void transpose_sb_to_bs(const float* __restrict__ in,
                                                          float* __restrict__ out)
{
  size_t m = blockIdx.x;
  size_t s = m >> 3, b = m & 7;
  const float4* src = (const float4*)(in + m * HID_);
  float4* dst = (float4*)(out + (b * (size_t)S_ + s) * HID_);
  dst[threadIdx.x] = src[threadIdx.x];
}

// ---------------------------------------------------------------------------
extern "C" void kernel_launch(void* const* d_in, const int* in_sizes, int n_in,
                              void* d_out, int out_size, void* d_ws, size_t ws_size,
                              hipStream_t stream)
{
  const float* x        = (const float*)d_in[0];
  const float* ip_w     = (const float*)d_in[1];
  const float* ip_b     = (const float*)d_in[2];
  const float* fw_ln_g  = (const float*)d_in[3];
  const float* fw_ln_b  = (const float*)d_in[4];
  const float* fw_slow_w = (const float*)d_in[5];
  const float* fw_out_w  = (const float*)d_in[6];
  const float* ff_ln_g  = (const float*)d_in[7];
  const float* ff_ln_b  = (const float*)d_in[8];
  const float* ff_w1    = (const float*)d_in[9];
  const float* ff_b1    = (const float*)d_in[10];
  const float* ff_w2    = (const float*)d_in[11];
  const float* ff_b2    = (const float*)d_in[12];
  float* out = (float*)d_out;

  const int M = B_ * S_;  // 16384
  const size_t matN = (size_t)64 * NCH_ * 4096;  // 8.39M elems per 64x64xchunk matrix

  size_t need = ((size_t)M * (HID_ + QKVB_ + HID_)) * sizeof(float);
  if (ws_size < need) return;

  float* cur  = (float*)d_ws;
  float* qkvb = cur + (size_t)M * HID_;
  float* attn = qkvb + (size_t)M * QKVB_;
  // delta scratch aliases: MT,N (bf16) fill the attn slot; CK,U0T (bf16) fill d_out;
  // W0 snapshots (fp32) overwrite the dead V region inside qkvb.
  u16*   MTg  = (u16*)attn;
  u16*   Ng   = MTg + matN;
  u16*   CKg  = (u16*)out;
  u16*   U0Tg = CKg + matN;
  float* big  = qkvb;     // FFN hidden aliases qkvb+attn region
  float* tmp  = out;      // LN scratch; dead during the delta phase

  dim3 blk(256);

  gemm_mfma<true, false, false, true><<<dim3(HID_ / 128, M / 128), blk, 0, stream>>>(
      x, ip_w, ip_b, nullptr, cur, M, HID_, HID_);

  for (int layer = 0; layer < 2; ++layer) {
    const float* sw = fw_slow_w + (size_t)layer * QKVB_ * HID_;
    const float* ow = fw_out_w  + (size_t)layer * HID_ * HID_;

    ln_k<<<M, 64, 0, stream>>>(cur, fw_ln_g + layer * HID_, fw_ln_b + layer * HID_, tmp);
    gemm_mfma<false, false, false, false><<<dim3((QKVB_ + 127) / 128, M / 128), blk, 0, stream>>>(
        tmp, sw, nullptr, nullptr, qkvb, M, QKVB_, HID_);
    qkvb_transform<<<(size_t)M * H_, 64, 0, stream>>>(qkvb);
    delta_p1<<<64 * NCH_, 256, 0, stream>>>(qkvb, MTg, Ng, CKg, U0Tg);
    delta_p2<<<64, 256, 0, stream>>>(MTg, Ng, qkvb);
    delta_p3<<<64 * NCH_, 256, 0, stream>>>(qkvb, CKg, U0Tg, attn);
    gemm_mfma<false, false, true, false><<<dim3(HID_ / 128, M / 128), blk, 0, stream>>>(
        attn, ow, nullptr, cur, cur, M, HID_, HID_);

    if (layer == 0) {
      ln_k<<<M, 64, 0, stream>>>(cur, ff_ln_g, ff_ln_b, tmp);
      gemm_mfma<true, true, false, false><<<dim3(FF_ / 128, M / 128), blk, 0, stream>>>(
          tmp, ff_w1, ff_b1, nullptr, big, M, FF_, HID_);
      gemm_mfma<true, false, true, false><<<dim3(HID_ / 128, M / 128), blk, 0, stream>>>(
          big, ff_w2, ff_b2, cur, cur, M, HID_, FF_);
    }
  }

  transpose_sb_to_bs<<<M, 128, 0, stream>>>(cur, out);
}

// Round 6
// 707.064 us; speedup vs baseline: 9.5647x; 1.2486x over previous
//
#include <hip/hip_runtime.h>
#include <hip/hip_bf16.h>

#define B_    8
#define S_    2048
#define HID_  512
#define H_    8
#define D_    64
#define FF_   2048
#define QKVB_ 1544   // H*(3*D+1) = 8*193
#define NCH_  32     // S/64 chunks

typedef unsigned short u16;
typedef __attribute__((ext_vector_type(8))) short short8;
typedef __attribute__((ext_vector_type(4))) float f32x4;

__device__ __forceinline__ u16 f2bf(float x) {           // RNE fp32->bf16
  unsigned u = __builtin_bit_cast(unsigned, x);
  unsigned r = (u + 0x7FFFu + ((u >> 16) & 1u)) >> 16;
  return (u16)r;
}
__device__ __forceinline__ float bf2f(u16 v) {
  return __builtin_bit_cast(float, (unsigned)v << 16);
}
__device__ __forceinline__ void gload16(const void* g, void* l) {
  __builtin_amdgcn_global_load_lds(
      (const __attribute__((address_space(1))) unsigned int*)g,
      (__attribute__((address_space(3))) unsigned int*)l, 16, 0, 0);
}

// 64x64x64 product C[r][c] = sum_k F[r][k]*G[c][k], bf16 LDS operands.
template<int FS, int GS>
__device__ __forceinline__ void prod64(const u16* __restrict__ F,
                                       const u16* __restrict__ G,
                                       int wrow0, int lane, f32x4 acc[4])
{
  short8 f0 = *(const short8*)&F[(wrow0 + (lane & 15)) * FS + ((lane >> 4) * 8)];
  short8 f1 = *(const short8*)&F[(wrow0 + (lane & 15)) * FS + 32 + ((lane >> 4) * 8)];
  #pragma unroll
  for (int c0 = 0; c0 < 4; ++c0) {
    short8 g0 = *(const short8*)&G[(c0 * 16 + (lane & 15)) * GS + ((lane >> 4) * 8)];
    short8 g1 = *(const short8*)&G[(c0 * 16 + (lane & 15)) * GS + 32 + ((lane >> 4) * 8)];
    acc[c0] = __builtin_amdgcn_mfma_f32_16x16x32_bf16(f0, g0, acc[c0], 0, 0, 0);
    acc[c0] = __builtin_amdgcn_mfma_f32_16x16x32_bf16(f1, g1, acc[c0], 0, 0, 0);
  }
}

// ---------------------------------------------------------------------------
// bf16 GEMM, bf16 operands in HBM, global_load_lds staging, swizzled LDS.
// C[m,n] = epilogue( sum_k A[m,k] * W[n,k] ).  128x128 tile, BK=64, 4 waves.
// Staging: linear LDS dest (gload_lds), inverse-swizzled global source;
// ds_read applies byte ^= ((row&7)<<4)  (rule #21 both-sides swizzle).
// ---------------------------------------------------------------------------
template<bool BIAS, bool RELU, bool RES, bool OUTBF>
__global__ __launch_bounds__(256) void gemm_bf(
    const u16* __restrict__ A, const u16* __restrict__ W,
    const float* __restrict__ bias, const float* __restrict__ res,
    void* __restrict__ Cout, int M, int N, int K)
{
  __shared__ __align__(16) u16 As[128 * 64];
  __shared__ __align__(16) u16 Bs[128 * 64];
  const int tid = threadIdx.x, lane = tid & 63, wv = tid >> 6;
  const int bm = blockIdx.y * 128, bn = blockIdx.x * 128;
  const int wr = wv >> 1, wc = wv & 1;
  const int row16 = lane & 15, kg = lane >> 4;
  const int srow = lane >> 3;                                   // 0..7
  const int soff = ((lane & 7) * 16) ^ (srow << 4);             // swizzled src byte

  f32x4 acc[4][4] = {};
  const int ktiles = K >> 6;

  for (int kt = 0; kt < ktiles; ++kt) {
    #pragma unroll
    for (int i = 0; i < 4; ++i) {
      const int r = i * 32 + wv * 8;                            // wave-uniform
      const char* ga = (const char*)(A + (size_t)(bm + r + srow) * K + (size_t)kt * 64) + soff;
      gload16(ga, &As[r * 64]);
      const char* gw = (const char*)(W + (size_t)(bn + r + srow) * K + (size_t)kt * 64) + soff;
      gload16(gw, &Bs[r * 64]);
    }
    __syncthreads();   // drains vmcnt -> LDS ready

    #pragma unroll
    for (int kh = 0; kh < 2; ++kh) {
      const int fb = ((kh * 64 + kg * 16) ^ ((row16 & 7) << 4)) >> 1;  // u16 idx in row
      short8 af[4], bf_[4];
      #pragma unroll
      for (int m = 0; m < 4; ++m)
        af[m] = *(const short8*)&As[(wr * 64 + m * 16 + row16) * 64 + fb];
      #pragma unroll
      for (int n = 0; n < 4; ++n)
        bf_[n] = *(const short8*)&Bs[(wc * 64 + n * 16 + row16) * 64 + fb];
      #pragma unroll
      for (int m = 0; m < 4; ++m)
        #pragma unroll
        for (int n = 0; n < 4; ++n)
          acc[m][n] = __builtin_amdgcn_mfma_f32_16x16x32_bf16(af[m], bf_[n], acc[m][n], 0, 0, 0);
    }
    __syncthreads();   // all reads done before next overwrite
  }

  #pragma unroll
  for (int m = 0; m < 4; ++m) {
    #pragma unroll
    for (int n = 0; n < 4; ++n) {
      const int gcol = bn + wc * 64 + n * 16 + row16;
      if (gcol < N) {
        #pragma unroll
        for (int j = 0; j < 4; ++j) {
          const int grow = bm + wr * 64 + m * 16 + kg * 4 + j;
          float v = acc[m][n][j];
          if (BIAS) v += bias[gcol];
          if (RES)  v += res[(size_t)grow * N + gcol];
          if (RELU) v = fmaxf(v, 0.f);
          if (OUTBF) ((u16*)Cout)[(size_t)grow * N + gcol] = f2bf(v);
          else       ((float*)Cout)[(size_t)grow * N + gcol] = v;
        }
      }
    }
  }
}

// ---------------------------------------------------------------------------
// Converters
// ---------------------------------------------------------------------------
__global__ __launch_bounds__(256) void conv_w(const float* __restrict__ s,
                                              u16* __restrict__ d, int n, int npad)
{
  int i = blockIdx.x * 256 + threadIdx.x;
  if (i < npad) d[i] = (i < n) ? f2bf(s[i]) : (u16)0;
}

// x [B,S,512] fp32 -> xbf [S,B,512] bf16
__global__ __launch_bounds__(64) void conv_x(const float* __restrict__ x,
                                             u16* __restrict__ xbf)
{
  size_t m = blockIdx.x;                 // s*B + b
  size_t s = m >> 3, b = m & 7;
  const float4* src = (const float4*)(x + (b * (size_t)S_ + s) * HID_);
  float4 v0 = src[threadIdx.x], v1 = src[64 + threadIdx.x];
  u16* dst = xbf + m * HID_;
  uint2 p0, p1;
  p0.x = (unsigned)f2bf(v0.x) | ((unsigned)f2bf(v0.y) << 16);
  p0.y = (unsigned)f2bf(v0.z) | ((unsigned)f2bf(v0.w) << 16);
  p1.x = (unsigned)f2bf(v1.x) | ((unsigned)f2bf(v1.y) << 16);
  p1.y = (unsigned)f2bf(v1.z) | ((unsigned)f2bf(v1.w) << 16);
  *(uint2*)&dst[threadIdx.x * 4] = p0;
  *(uint2*)&dst[256 + threadIdx.x * 4] = p1;
}

// ---------------------------------------------------------------------------
// LayerNorm -> bf16 output
// ---------------------------------------------------------------------------
__global__ __launch_bounds__(64) void ln_bf(const float* __restrict__ x,
    const float* __restrict__ g, const float* __restrict__ bt,
    u16* __restrict__ o)
{
  size_t row = blockIdx.x;
  int lane = threadIdx.x;
  const float4* xr = (const float4*)(x + row * HID_);
  float4 v0 = xr[lane];
  float4 v1 = xr[64 + lane];
  float s  = v0.x + v0.y + v0.z + v0.w + v1.x + v1.y + v1.z + v1.w;
  float ss = v0.x*v0.x + v0.y*v0.y + v0.z*v0.z + v0.w*v0.w
           + v1.x*v1.x + v1.y*v1.y + v1.z*v1.z + v1.w*v1.w;
  #pragma unroll
  for (int off = 32; off; off >>= 1) {
    s  += __shfl_xor(s, off);
    ss += __shfl_xor(ss, off);
  }
  float mean = s * (1.f / HID_);
  float inv  = rsqrtf(ss * (1.f / HID_) - mean * mean + 1e-5f);
  const float4* gv = (const float4*)g;
  const float4* bv = (const float4*)bt;
  float4 g0 = gv[lane], g1 = gv[64 + lane];
  float4 b0 = bv[lane], b1 = bv[64 + lane];
  uint2 p0, p1;
  p0.x = (unsigned)f2bf((v0.x - mean) * inv * g0.x + b0.x)
       | ((unsigned)f2bf((v0.y - mean) * inv * g0.y + b0.y) << 16);
  p0.y = (unsigned)f2bf((v0.z - mean) * inv * g0.z + b0.z)
       | ((unsigned)f2bf((v0.w - mean) * inv * g0.w + b0.w) << 16);
  p1.x = (unsigned)f2bf((v1.x - mean) * inv * g1.x + b1.x)
       | ((unsigned)f2bf((v1.y - mean) * inv * g1.y + b1.y) << 16);
  p1.y = (unsigned)f2bf((v1.z - mean) * inv * g1.z + b1.z)
       | ((unsigned)f2bf((v1.w - mean) * inv * g1.w + b1.w) << 16);
  u16* ov = o + row * HID_;
  *(uint2*)&ov[lane * 4] = p0;
  *(uint2*)&ov[256 + lane * 4] = p1;
}

// ---------------------------------------------------------------------------
__global__ __launch_bounds__(64) void qkvb_transform(float* __restrict__ qkvb)
{
  size_t r = blockIdx.x;
  float* base = qkvb + (r >> 3) * (size_t)QKVB_ + (r & 7) * 193;
  int lane = threadIdx.x;
  float q = base[lane], k = base[64 + lane];
  float mq = q, mk = k;
  #pragma unroll
  for (int off = 32; off; off >>= 1) {
    mq = fmaxf(mq, __shfl_xor(mq, off));
    mk = fmaxf(mk, __shfl_xor(mk, off));
  }
  float eq = __expf(q - mq), ek = __expf(k - mk);
  float sq = eq, sk = ek;
  #pragma unroll
  for (int off = 32; off; off >>= 1) { sq += __shfl_xor(sq, off); sk += __shfl_xor(sk, off); }
  base[lane]      = eq / sq;
  base[64 + lane] = ek / sk;
  if (lane == 0) { float bb = base[192]; base[192] = 1.f / (1.f + __expf(-bb)); }
}

// ---------------------------------------------------------------------------
// Delta rule, 3-phase chunked WY form (unchanged math from round 5).
// ---------------------------------------------------------------------------
__global__ __launch_bounds__(256, 2) void delta_p1(const float* __restrict__ qkvb,
                                                   u16* __restrict__ MTg,
                                                   u16* __restrict__ Ng,
                                                   u16* __restrict__ CKg,
                                                   u16* __restrict__ U0Tg)
{
  __shared__ __align__(16) u16 Kb[64 * 72];
  __shared__ __align__(16) float Am[64][65];
  __shared__ __align__(16) float Uv[64][65];
  __shared__ __align__(16) float Uk[64][65];
  __shared__ __align__(16) u16 CKTb[64 * 72];
  __shared__ __align__(16) u16 U0Tb[64 * 72];
  __shared__ float bet[64];
  u16* KTb = (u16*)&Am[0][0];   // stride 88

  const int id5 = blockIdx.x, bh = id5 >> 5;
  const int b = bh & 7, h = bh >> 3, t0 = (id5 & 31) * 64;
  const int tid = threadIdx.x, lane = tid & 63, wv = tid >> 6;
  const int wid = wv, wrow0 = wv * 16;
  const size_t hoff = (size_t)h * 193;

  #pragma unroll
  for (int i = 0; i < 16; ++i) {
    int idx = i * 256 + tid, row = idx >> 6, col = idx & 63;
    size_t gb = ((size_t)(t0 + row) * B_ + b) * QKVB_ + hoff;
    Kb[row * 72 + col] = f2bf(qkvb[gb + 64 + col]);
  }
  if (tid < 64) bet[tid] = qkvb[((size_t)(t0 + tid) * B_ + b) * QKVB_ + hoff + 192];
  __syncthreads();

  {
    f32x4 a[4] = {};
    prod64<72, 72>(Kb, Kb, wrow0, lane, a);
    #pragma unroll
    for (int c0 = 0; c0 < 4; ++c0)
      #pragma unroll
      for (int j = 0; j < 4; ++j) {
        int row = wrow0 + (lane >> 4) * 4 + j, col = c0 * 16 + (lane & 15);
        Am[row][col] = bet[row] * a[c0][j];
      }
  }
  #pragma unroll
  for (int i = 0; i < 16; ++i) {
    int idx = i * 256 + tid, row = idx >> 6, col = idx & 63;
    size_t gb = ((size_t)(t0 + row) * B_ + b) * QKVB_ + hoff;
    float bt_ = bet[row];
    Uv[row][col] = bt_ * qkvb[gb + 128 + col];
    Uk[row][col] = bt_ * bf2f(Kb[row * 72 + col]);
  }
  __syncthreads();

  #pragma unroll 1
  for (int blk = 0; blk < 4; ++blk) {
    if (wid == blk) {
      const int r0 = blk * 16;
      float uv[16], uk[16];
      #pragma unroll
      for (int i = 0; i < 16; ++i) { uv[i] = Uv[r0 + i][lane]; uk[i] = Uk[r0 + i][lane]; }
      #pragma unroll
      for (int jj = 0; jj < 15; ++jj) {
        #pragma unroll
        for (int t = jj + 1; t < 16; ++t) {
          float a = Am[r0 + t][r0 + jj];
          uv[t] = fmaf(-a, uv[jj], uv[t]);
          uk[t] = fmaf(-a, uk[jj], uk[t]);
        }
      }
      #pragma unroll
      for (int i = 0; i < 16; ++i) { Uv[r0 + i][lane] = uv[i]; Uk[r0 + i][lane] = uk[i]; }
    }
    __syncthreads();
    if (wid > blk) {
      const int r0 = blk * 16, rw = wid * 16;
      float uv[16], uk[16];
      #pragma unroll
      for (int i = 0; i < 16; ++i) { uv[i] = Uv[rw + i][lane]; uk[i] = Uk[rw + i][lane]; }
      #pragma unroll
      for (int jj = 0; jj < 16; ++jj) {
        float sv = Uv[r0 + jj][lane], sk = Uk[r0 + jj][lane];
        #pragma unroll
        for (int i = 0; i < 16; ++i) {
          float a = Am[rw + i][r0 + jj];
          uv[i] = fmaf(-a, sv, uv[i]);
          uk[i] = fmaf(-a, sk, uk[i]);
        }
      }
      #pragma unroll
      for (int i = 0; i < 16; ++i) { Uv[rw + i][lane] = uv[i]; Uk[rw + i][lane] = uk[i]; }
    }
    __syncthreads();
  }

  const int prow = tid >> 2, pc0 = (tid & 3) * 16;
  const size_t mb = (size_t)id5 * 4096;
  {
    union { u16 u[16]; uint4 v[2]; } pk, pu;
    #pragma unroll
    for (int i = 0; i < 16; ++i) pk.u[i] = f2bf(Uk[prow][pc0 + i]);
    #pragma unroll
    for (int i = 0; i < 16; ++i) pu.u[i] = f2bf(Uv[pc0 + i][prow]);
    *(uint4*)&CKg[mb + prow * 64 + pc0]      = pk.v[0];
    *(uint4*)&CKg[mb + prow * 64 + pc0 + 8]  = pk.v[1];
    *(uint4*)&U0Tg[mb + prow * 64 + pc0]     = pu.v[0];
    *(uint4*)&U0Tg[mb + prow * 64 + pc0 + 8] = pu.v[1];
    *(short8*)&U0Tb[prow * 72 + pc0]     = *(short8*)&pu.u[0];
    *(short8*)&U0Tb[prow * 72 + pc0 + 8] = *(short8*)&pu.u[8];
    #pragma unroll
    for (int i = 0; i < 16; ++i) CKTb[prow * 72 + pc0 + i] = f2bf(Uk[pc0 + i][prow]);
    #pragma unroll
    for (int i = 0; i < 16; ++i) KTb[prow * 88 + pc0 + i] = Kb[(pc0 + i) * 72 + prow];
  }
  __syncthreads();

  {
    f32x4 am[4] = {}, an[4] = {};
    prod64<88, 72>(KTb, CKTb, wrow0, lane, am);
    prod64<72, 88>(U0Tb, KTb, wrow0, lane, an);
    u16* MTs = (u16*)&Uv[0][0];
    u16* Ns  = (u16*)&Uk[0][0];
    #pragma unroll
    for (int c0 = 0; c0 < 4; ++c0)
      #pragma unroll
      for (int j = 0; j < 4; ++j) {
        int row = wrow0 + (lane >> 4) * 4 + j, col = c0 * 16 + (lane & 15);
        MTs[row * 64 + col] = f2bf(am[c0][j]);
        Ns[row * 64 + col]  = f2bf(an[c0][j]);
      }
  }
  __syncthreads();
  {
    const u16* MTs = (const u16*)&Uv[0][0];
    const u16* Ns  = (const u16*)&Uk[0][0];
    *(uint4*)&MTg[mb + prow * 64 + pc0]     = ((const uint4*)&MTs[prow * 64 + pc0])[0];
    *(uint4*)&MTg[mb + prow * 64 + pc0 + 8] = ((const uint4*)&MTs[prow * 64 + pc0])[1];
    *(uint4*)&Ng[mb + prow * 64 + pc0]      = ((const uint4*)&Ns[prow * 64 + pc0])[0];
    *(uint4*)&Ng[mb + prow * 64 + pc0 + 8]  = ((const uint4*)&Ns[prow * 64 + pc0])[1];
  }
}

__global__ __launch_bounds__(256, 1) void delta_p2(const u16* __restrict__ MTg,
                                                   const u16* __restrict__ Ng,
                                                   float* __restrict__ qkvb)
{
  __shared__ float Ws[64][65];
  __shared__ __align__(16) u16 Wbf[64 * 72];
  __shared__ __align__(16) u16 MTb[64 * 72];
  __shared__ __align__(16) u16 Nb[64 * 72];
  const int bh = blockIdx.x, b = bh & 7, h = bh >> 3;
  const int tid = threadIdx.x, lane = tid & 63, wv = tid >> 6, wrow0 = wv * 16;
  const size_t hoff = (size_t)h * 193;
  const int prow = tid >> 2, pc0 = (tid & 3) * 16;

  for (int i = tid; i < 64 * 65; i += 256) (&Ws[0][0])[i] = 0.f;
  for (int i = tid; i < 64 * 72; i += 256) Wbf[i] = 0;
  __syncthreads();

  for (int j = 0; j < NCH_; ++j) {
    size_t base = ((size_t)bh * NCH_ + j) * 4096;
    {
      uint4 m0 = *(const uint4*)&MTg[base + prow * 64 + pc0];
      uint4 m1 = *(const uint4*)&MTg[base + prow * 64 + pc0 + 8];
      uint4 n0 = *(const uint4*)&Ng[base + prow * 64 + pc0];
      uint4 n1 = *(const uint4*)&Ng[base + prow * 64 + pc0 + 8];
      *(short8*)&MTb[prow * 72 + pc0]     = __builtin_bit_cast(short8, m0);
      *(short8*)&MTb[prow * 72 + pc0 + 8] = __builtin_bit_cast(short8, m1);
      *(short8*)&Nb[prow * 72 + pc0]      = __builtin_bit_cast(short8, n0);
      *(short8*)&Nb[prow * 72 + pc0 + 8]  = __builtin_bit_cast(short8, n1);
    }
    {
      const int t0 = j * 64;
      #pragma unroll
      for (int i = 0; i < 16; ++i)
        qkvb[((size_t)(t0 + prow) * B_ + b) * QKVB_ + hoff + 128 + pc0 + i] = Ws[prow][pc0 + i];
    }
    __syncthreads();
    f32x4 a[4] = {};
    prod64<72, 72>(Wbf, MTb, wrow0, lane, a);
    #pragma unroll
    for (int c0 = 0; c0 < 4; ++c0)
      #pragma unroll
      for (int jj = 0; jj < 4; ++jj) {
        int row = wrow0 + (lane >> 4) * 4 + jj, col = c0 * 16 + (lane & 15);
        float w = Ws[row][col] + bf2f(Nb[row * 72 + col]) - a[c0][jj];
        Ws[row][col] = w;
        Wbf[row * 72 + col] = f2bf(w);
      }
    __syncthreads();
  }
}

__global__ __launch_bounds__(256, 2) void delta_p3(const float* __restrict__ qkvb,
                                                   const u16* __restrict__ CKg,
                                                   const u16* __restrict__ U0Tg,
                                                   u16* __restrict__ attnb)
{
  __shared__ __align__(16) u16 Qb[64 * 72];
  __shared__ __align__(16) u16 Kb[64 * 72];
  __shared__ __align__(16) u16 W0b[64 * 72];
  __shared__ __align__(16) u16 CKb[64 * 72];
  __shared__ __align__(16) u16 U0Tb[64 * 72];
  __shared__ __align__(16) u16 Gb[64 * 72];
  __shared__ __align__(16) u16 UTb[64 * 72];

  const int id5 = blockIdx.x, bh = id5 >> 5;
  const int b = bh & 7, h = bh >> 3, t0 = (id5 & 31) * 64;
  const int tid = threadIdx.x, lane = tid & 63, wv = tid >> 6, wrow0 = wv * 16;
  const size_t hoff = (size_t)h * 193;
  const int prow = tid >> 2, pc0 = (tid & 3) * 16;
  const size_t mb = (size_t)id5 * 4096;

  #pragma unroll
  for (int i = 0; i < 16; ++i) {
    int idx = i * 256 + tid, row = idx >> 6, col = idx & 63;
    size_t gb = ((size_t)(t0 + row) * B_ + b) * QKVB_ + hoff;
    Qb[row * 72 + col]  = f2bf(qkvb[gb + col]);
    Kb[row * 72 + col]  = f2bf(qkvb[gb + 64 + col]);
    W0b[row * 72 + col] = f2bf(qkvb[gb + 128 + col]);
  }
  {
    uint4 c0v = *(const uint4*)&CKg[mb + prow * 64 + pc0];
    uint4 c1v = *(const uint4*)&CKg[mb + prow * 64 + pc0 + 8];
    uint4 u0v = *(const uint4*)&U0Tg[mb + prow * 64 + pc0];
    uint4 u1v = *(const uint4*)&U0Tg[mb + prow * 64 + pc0 + 8];
    *(short8*)&CKb[prow * 72 + pc0]      = __builtin_bit_cast(short8, c0v);
    *(short8*)&CKb[prow * 72 + pc0 + 8]  = __builtin_bit_cast(short8, c1v);
    *(short8*)&U0Tb[prow * 72 + pc0]     = __builtin_bit_cast(short8, u0v);
    *(short8*)&U0Tb[prow * 72 + pc0 + 8] = __builtin_bit_cast(short8, u1v);
  }
  __syncthreads();

  f32x4 ag[4] = {}, ac[4] = {}, ab[4] = {};
  prod64<72, 72>(Qb, Kb, wrow0, lane, ag);
  prod64<72, 72>(W0b, CKb, wrow0, lane, ac);
  prod64<72, 72>(Qb, W0b, wrow0, lane, ab);

  #pragma unroll
  for (int c0 = 0; c0 < 4; ++c0)
    #pragma unroll
    for (int j = 0; j < 4; ++j) {
      int row = wrow0 + (lane >> 4) * 4 + j, col = c0 * 16 + (lane & 15);
      Gb[row * 72 + col]  = f2bf(col <= row ? ag[c0][j] : 0.f);
      UTb[row * 72 + col] = f2bf(bf2f(U0Tb[row * 72 + col]) - ac[c0][j]);
    }
  __syncthreads();

  prod64<72, 72>(Gb, UTb, wrow0, lane, ab);

  #pragma unroll
  for (int c0 = 0; c0 < 4; ++c0)
    #pragma unroll
    for (int j = 0; j < 4; ++j) {
      int row = wrow0 + (lane >> 4) * 4 + j, col = c0 * 16 + (lane & 15);
      attnb[((size_t)(t0 + row) * B_ + b) * HID_ + h * 64 + col] = f2bf(ab[c0][j]);
    }
}

// ---------------------------------------------------------------------------
__global__ __launch_bounds__(128) void transpose_sb_to_bs(const float* __restrict__ in,
                                                          float* __restrict__ out)
{
  size_t m = blockIdx.x;
  size_t s = m >> 3, b = m & 7;
  const float4* src = (const float4*)(in + m * HID_);
  float4* dst = (float4*)(out + (b * (size_t)S_ + s) * HID_);
  dst[threadIdx.x] = src[threadIdx.x];
}

// ---------------------------------------------------------------------------
extern "C" void kernel_launch(void* const* d_in, const int* in_sizes, int n_in,
                              void* d_out, int out_size, void* d_ws, size_t ws_size,
                              hipStream_t stream)
{
  const float* x        = (const float*)d_in[0];
  const float* ip_w     = (const float*)d_in[1];
  const float* ip_b     = (const float*)d_in[2];
  const float* fw_ln_g  = (const float*)d_in[3];
  const float* fw_ln_b  = (const float*)d_in[4];
  const float* fw_slow_w = (const float*)d_in[5];
  const float* fw_out_w  = (const float*)d_in[6];
  const float* ff_ln_g  = (const float*)d_in[7];
  const float* ff_ln_b  = (const float*)d_in[8];
  const float* ff_w1    = (const float*)d_in[9];
  const float* ff_b1    = (const float*)d_in[10];
  const float* ff_w2    = (const float*)d_in[11];
  const float* ff_b2    = (const float*)d_in[12];
  float* out = (float*)d_out;

  const int M = B_ * S_;  // 16384
  const size_t matN = (size_t)64 * NCH_ * 4096;   // 8.39M elems
  const int SLOWPAD = 1664;                       // 13*128 rows

  // bf16 pool sizes (u16 elems)
  const size_t nIp = 512 * 512, nOut = 512 * 512;
  const size_t nSlow = (size_t)SLOWPAD * 512;
  const size_t nW1 = (size_t)FF_ * 512, nW2 = (size_t)512 * FF_;
  const size_t nXbf = (size_t)M * HID_;
  const size_t poolElems = nIp + 2 * nSlow + 2 * nOut + nW1 + nW2 + nXbf;

  size_t need = ((size_t)M * (HID_ + QKVB_ + HID_)) * sizeof(float) + poolElems * 2;
  if (ws_size < need) return;

  float* cur  = (float*)d_ws;
  float* qkvb = cur + (size_t)M * HID_;
  float* attnSlot = qkvb + (size_t)M * QKVB_;
  u16*   MTg  = (u16*)attnSlot;
  u16*   Ng   = MTg + matN;
  u16*   attnb = (u16*)attnSlot;                  // reuses MTg region after p2
  u16*   CKg  = (u16*)out;
  u16*   U0Tg = CKg + matN;
  u16*   tmpbf = (u16*)out;                       // LN out; dead when CKg live
  u16*   hiddenb = (u16*)qkvb;                    // FFN hidden bf16

  u16* pool = (u16*)(attnSlot + (size_t)M * HID_);
  u16* ipwb   = pool;               pool += nIp;
  u16* slowb0 = pool;               pool += nSlow;
  u16* slowb1 = pool;               pool += nSlow;
  u16* outwb0 = pool;               pool += nOut;
  u16* outwb1 = pool;               pool += nOut;
  u16* w1b    = pool;               pool += nW1;
  u16* w2b    = pool;               pool += nW2;
  u16* xbf    = pool;

  dim3 blk(256);

  // weight + input conversions
  conv_w<<<(nIp + 255) / 256, blk, 0, stream>>>(ip_w, ipwb, nIp, nIp);
  conv_w<<<(nSlow + 255) / 256, blk, 0, stream>>>(fw_slow_w, slowb0, QKVB_ * 512, nSlow);
  conv_w<<<(nSlow + 255) / 256, blk, 0, stream>>>(fw_slow_w + (size_t)QKVB_ * 512, slowb1, QKVB_ * 512, nSlow);
  conv_w<<<(nOut + 255) / 256, blk, 0, stream>>>(fw_out_w, outwb0, nOut, nOut);
  conv_w<<<(nOut + 255) / 256, blk, 0, stream>>>(fw_out_w + (size_t)512 * 512, outwb1, nOut, nOut);
  conv_w<<<(nW1 + 255) / 256, blk, 0, stream>>>(ff_w1, w1b, nW1, nW1);
  conv_w<<<(nW2 + 255) / 256, blk, 0, stream>>>(ff_w2, w2b, nW2, nW2);
  conv_x<<<M, 64, 0, stream>>>(x, xbf);

  // input projection: cur = xbf @ ipw^T + b
  gemm_bf<true, false, false, false><<<dim3(4, 128), blk, 0, stream>>>(
      xbf, ipwb, ip_b, nullptr, cur, M, HID_, HID_);

  for (int layer = 0; layer < 2; ++layer) {
    u16* slowb = layer ? slowb1 : slowb0;
    u16* outwb = layer ? outwb1 : outwb0;

    ln_bf<<<M, 64, 0, stream>>>(cur, fw_ln_g + layer * HID_, fw_ln_b + layer * HID_, tmpbf);
    gemm_bf<false, false, false, false><<<dim3(13, 128), blk, 0, stream>>>(
        tmpbf, slowb, nullptr, nullptr, qkvb, M, QKVB_, HID_);
    qkvb_transform<<<(size_t)M * H_, 64, 0, stream>>>(qkvb);
    delta_p1<<<64 * NCH_, 256, 0, stream>>>(qkvb, MTg, Ng, CKg, U0Tg);
    delta_p2<<<64, 256, 0, stream>>>(MTg, Ng, qkvb);
    delta_p3<<<64 * NCH_, 256, 0, stream>>>(qkvb, CKg, U0Tg, attnb);
    gemm_bf<false, false, true, false><<<dim3(4, 128), blk, 0, stream>>>(
        attnb, outwb, nullptr, cur, cur, M, HID_, HID_);

    if (layer == 0) {
      ln_bf<<<M, 64, 0, stream>>>(cur, ff_ln_g, ff_ln_b, tmpbf);
      gemm_bf<true, true, false, true><<<dim3(16, 128), blk, 0, stream>>>(
          tmpbf, w1b, ff_b1, nullptr, hiddenb, M, FF_, HID_);
      gemm_bf<true, false, true, false><<<dim3(4, 128), blk, 0, stream>>>(
          hiddenb, w2b, ff_b2, cur, cur, M, HID_, FF_);
    }
  }

  transpose_sb_to_bs<<<M, 128, 0, stream>>>(cur, out);
}